// Round 5
// baseline (309.809 us; speedup 1.0000x reference)
//
#include <hip/hip_runtime.h>
#include <hip/hip_bf16.h>

#define B_    4
#define N_    8192
#define TOT   (B_*N_)      // 32768 points
#define KNN_  16
#define PPW   8            // points per wave in k2
#define PITCH 80           // LDS tile pitch in halfs (160B, 16B-aligned rows)

typedef _Float16 half8  __attribute__((ext_vector_type(8)));
typedef _Float16 half4  __attribute__((ext_vector_type(4)));
typedef float    floatx4 __attribute__((ext_vector_type(4)));

#define MFMA16(A, Bv, C) __builtin_amdgcn_mfma_f32_16x16x32_f16((A), (Bv), (C), 0, 0, 0)

__device__ __forceinline__ void lds_fence(){
  asm volatile("s_waitcnt lgkmcnt(0)" ::: "memory");
}
__device__ __forceinline__ half8 h8_load_f32(const float* __restrict__ p){
  float4 a = *(const float4*)p;
  float4 b = *(const float4*)(p + 4);
  half8 r;
  r[0] = (_Float16)a.x; r[1] = (_Float16)a.y; r[2] = (_Float16)a.z; r[3] = (_Float16)a.w;
  r[4] = (_Float16)b.x; r[5] = (_Float16)b.y; r[6] = (_Float16)b.z; r[7] = (_Float16)b.w;
  return r;
}

// Fill LDS B-fragment array for a 64x64 row-major f32 weight.
// Layout: frag index (kt*4+nt)*64 + lane; lane holds W[kt*32+quad*8+j][nt*16+(lane&15)].
__device__ void fill_w64(half8* dst, const float* __restrict__ W, int tid){
  for (int i = tid; i < 512; i += 256){
    int lane = i & 63, nt = (i >> 6) & 3, kt = i >> 8;
    int n  = nt*16 + (lane & 15);
    int kb = kt*32 + ((lane >> 4) & 3)*8;
    half8 v;
    #pragma unroll
    for (int j = 0; j < 8; j++) v[j] = (_Float16)W[(kb + j)*64 + n];
    dst[i] = v;
  }
}

// ---------------- kernel 1: x = fc1(features); q/xk/xv = x @ {wq,wk,wv} ----------------
__global__ __launch_bounds__(256, 3) void k1_qkv(
    const float* __restrict__ feat, const float* __restrict__ fc1w, const float* __restrict__ fc1b,
    const float* __restrict__ wqw, const float* __restrict__ wkw, const float* __restrict__ wvw,
    _Float16* __restrict__ qws, _Float16* __restrict__ kws, _Float16* __restrict__ vws)
{
  __shared__ half8 Sfc1[512], Sq[512], Sk[512], Sv[512];
  __shared__ alignas(16) _Float16 xt[4][16*PITCH];
  const int tid = threadIdx.x;
  fill_w64(Sfc1, fc1w, tid);
  fill_w64(Sq, wqw, tid);
  fill_w64(Sk, wkw, tid);
  fill_w64(Sv, wvw, tid);
  __syncthreads();

  const int wave = tid >> 6, lane = tid & 63, quad = lane >> 4, m16 = lane & 15;
  _Float16* tx = &xt[wave][0];
  const int rowbase = blockIdx.x*64 + wave*16;
  float fb[4];
  #pragma unroll
  for (int nt = 0; nt < 4; nt++) fb[nt] = fc1b[nt*16 + m16];

  const int arow = rowbase + m16;
  half8 Fa0 = h8_load_f32(&feat[arow*64 + quad*8]);
  half8 Fa1 = h8_load_f32(&feat[arow*64 + 32 + quad*8]);
  const floatx4 z4 = {0.f, 0.f, 0.f, 0.f};

  #pragma unroll
  for (int nt = 0; nt < 4; nt++){
    floatx4 acc = MFMA16(Fa0, Sfc1[nt*64 + lane], z4);
    acc = MFMA16(Fa1, Sfc1[(4 + nt)*64 + lane], acc);
    const int col = nt*16 + m16;
    #pragma unroll
    for (int r = 0; r < 4; r++)
      tx[(quad*4 + r)*PITCH + col] = (_Float16)(acc[r] + fb[nt]);
  }
  lds_fence();
  const half8 Ax0 = *(const half8*)&tx[m16*PITCH + quad*8];
  const half8 Ax1 = *(const half8*)&tx[m16*PITCH + 32 + quad*8];

#define EMIT_QKV(S, OUT)                                                      \
  { _Pragma("unroll")                                                         \
    for (int nt = 0; nt < 4; nt++){                                           \
      floatx4 acc = MFMA16(Ax0, S[nt*64 + lane], z4);                         \
      acc = MFMA16(Ax1, S[(4 + nt)*64 + lane], acc);                          \
      _Pragma("unroll")                                                       \
      for (int r = 0; r < 4; r++)                                             \
        OUT[(rowbase + quad*4 + r)*64 + nt*16 + m16] = (_Float16)acc[r];      \
    } }
  EMIT_QKV(Sq, qws)
  EMIT_QKV(Sk, kws)
  EMIT_QKV(Sv, vws)
#undef EMIT_QKV
}

// ---------------- kernel 2: per-point fused pos_enc / attention ----------------
__global__ __launch_bounds__(256, 4) void k2_point(
    const float* __restrict__ xyz, const int* __restrict__ knn,
    const float* __restrict__ d1w, const float* __restrict__ d1b,
    const float* __restrict__ d2w, const float* __restrict__ d2b,
    const float* __restrict__ g1w, const float* __restrict__ g1b,
    const float* __restrict__ g2w, const float* __restrict__ g2b,
    const _Float16* __restrict__ qws, const _Float16* __restrict__ kws,
    const _Float16* __restrict__ vws,
    _Float16* __restrict__ r0, float* __restrict__ attn_out)
{
  __shared__ half8 Sd2[512], Sg1[512], Sg2[512];
  __shared__ float4 Td1[64];                       // d1^T columns: {w0,w1,w2,bias}
  // single tile per wave, reused for P (stage2), u (stage3), attn (epilogue).
  // Safe: wave-private + DS ops are in-order within a wave; every read is
  // consumed before the next aliasing write issues (compiler lgkmcnt waits).
  __shared__ alignas(16) _Float16 tiles[4][16*PITCH];
  const int tid = threadIdx.x;
  fill_w64(Sd2, d2w, tid);
  fill_w64(Sg1, g1w, tid);
  fill_w64(Sg2, g2w, tid);
  if (tid < 64)
    Td1[tid] = make_float4(d1w[tid], d1w[64 + tid], d1w[128 + tid], d1b[tid]);
  __syncthreads();

  const int wave = tid >> 6, lane = tid & 63, quad = lane >> 4, m16 = lane & 15;
  _Float16* tT = &tiles[wave][0];

  half8 Fd2[2][4], Fg1[2][4], Fg2[2][4];
  #pragma unroll
  for (int nt = 0; nt < 4; nt++){
    #pragma unroll
    for (int kt = 0; kt < 2; kt++){
      Fd2[kt][nt] = Sd2[(kt*4 + nt)*64 + lane];
      Fg1[kt][nt] = Sg1[(kt*4 + nt)*64 + lane];
      Fg2[kt][nt] = Sg2[(kt*4 + nt)*64 + lane];
    }
  }
  float bd2[4], bg1[4], bg2[4];
  #pragma unroll
  for (int nt = 0; nt < 4; nt++){
    const int c = nt*16 + m16;
    bd2[nt] = d2b[c]; bg1[nt] = g1b[c]; bg2[nt] = g2b[c];
  }
  const floatx4 z4 = {0.f, 0.f, 0.f, 0.f};
  // XOR bank swizzle: write col' = col ^ ((row>>2)<<3). Writers have row>>2 == quad;
  // A-layout readers (row m16) use (m16>>2); store-layout readers (row s*4+quad) use s.
  const int wsw = quad << 3;
  const int swz = (quad ^ (m16 >> 2)) << 3;

  const int gpt0 = blockIdx.x*(4*PPW) + wave*PPW;   // block covers 32 consecutive points
  const int b    = gpt0 >> 13;                      // N=8192; constant within block

  // ---- 1-deep software pipeline for the knn -> xyz gather chain ----
  int grow_c = b*N_ + knn[gpt0*KNN_ + m16];
  float xq0 = xyz[gpt0*3 + 0], xq1 = xyz[gpt0*3 + 1], xq2 = xyz[gpt0*3 + 2];
  float xn0 = xyz[grow_c*3 + 0], xn1 = xyz[grow_c*3 + 1], xn2 = xyz[grow_c*3 + 2];

  for (int p = 0; p < PPW; p++){
    const int gpt  = gpt0 + p;
    const int grow = grow_c;

    // ---- issue all of this point's gathers early, A-layout coalesced (16B/lane) ----
    const half8 Ka0 = *(const half8*)&kws[grow*64 + quad*8];
    const half8 Ka1 = *(const half8*)&kws[grow*64 + 32 + quad*8];
    const half8 Qa0 = *(const half8*)&qws[gpt*64 + quad*8];
    const half8 Qa1 = *(const half8*)&qws[gpt*64 + 32 + quad*8];
    const half8 Va0 = *(const half8*)&vws[grow*64 + quad*8];
    const half8 Va1 = *(const half8*)&vws[grow*64 + 32 + quad*8];

    // prefetch next point's knn row (xyz gather for it is issued at loop bottom)
    int grow_n = 0;
    if (p < PPW-1) grow_n = b*N_ + knn[(gpt+1)*KNN_ + m16];

    const float dx = xq0 - xn0, dy = xq1 - xn1, dz = xq2 - xn2;

    // ---- stage 1: t = relu(rel @ d1 + b), pure VALU, straight into A-layout regs ----
    half8 At0, At1;
    #pragma unroll
    for (int j = 0; j < 8; j++){
      const float4 w  = Td1[quad*8 + j];
      const float4 w2 = Td1[32 + quad*8 + j];
      float t  = fmaf(dx, w.x,  fmaf(dy, w.y,  fmaf(dz, w.z,  w.w)));
      float t2 = fmaf(dx, w2.x, fmaf(dy, w2.y, fmaf(dz, w2.z, w2.w)));
      At0[j] = (_Float16)(t  > 0.f ? t  : 0.f);
      At1[j] = (_Float16)(t2 > 0.f ? t2 : 0.f);
    }

    // ---- stage 2: P = t @ d2 + b -> swizzled tile ----
    #pragma unroll
    for (int nt = 0; nt < 4; nt++){
      floatx4 acc = MFMA16(At0, Fd2[0][nt], z4);
      acc = MFMA16(At1, Fd2[1][nt], acc);
      const int colS = (nt*16 + m16) ^ wsw;
      #pragma unroll
      for (int r = 0; r < 4; r++)
        tT[(quad*4 + r)*PITCH + colS] = (_Float16)(acc[r] + bd2[nt]);
    }
    lds_fence();
    const half8 Pa0 = *(const half8*)&tT[m16*PITCH + swz];
    const half8 Pa1 = *(const half8*)&tT[m16*PITCH + 32 + swz];
    const half8 H0 = Qa0 - Ka0 + Pa0;
    const half8 H1 = Qa1 - Ka1 + Pa1;

    // ---- stage 3: u = relu(H @ g1 + b) -> swizzled tile (reuses tT; in-order DS) ----
    #pragma unroll
    for (int nt = 0; nt < 4; nt++){
      floatx4 acc = MFMA16(H0, Fg1[0][nt], z4);
      acc = MFMA16(H1, Fg1[1][nt], acc);
      const int colS = (nt*16 + m16) ^ wsw;
      #pragma unroll
      for (int r = 0; r < 4; r++){
        float t = acc[r] + bg1[nt];
        tT[(quad*4 + r)*PITCH + colS] = (_Float16)(t > 0.f ? t : 0.f);
      }
    }
    lds_fence();
    const half8 U0 = *(const half8*)&tT[m16*PITCH + swz];
    const half8 U1 = *(const half8*)&tT[m16*PITCH + 32 + swz];

    // ---- stage 4: logits = u @ g2 + b (C layout) ----
    float A2[4][4];
    #pragma unroll
    for (int nt = 0; nt < 4; nt++){
      floatx4 acc = MFMA16(U0, Fg2[0][nt], z4);
      acc = MFMA16(U1, Fg2[1][nt], acc);
      #pragma unroll
      for (int r = 0; r < 4; r++) A2[nt][r] = acc[r] + bg2[nt];
    }

    // ---- softmax over 16 neighbor rows (C layout: 4 local + cross-quad shfls) ----
    #pragma unroll
    for (int nt = 0; nt < 4; nt++){
      float mx = fmaxf(fmaxf(A2[nt][0], A2[nt][1]), fmaxf(A2[nt][2], A2[nt][3]));
      mx = fmaxf(mx, __shfl_xor(mx, 16));
      mx = fmaxf(mx, __shfl_xor(mx, 32));
      float s = 0.f;
      #pragma unroll
      for (int r = 0; r < 4; r++){
        float e = exp2f((A2[nt][r] - mx)*0.18033688011112042f);  // /8, base-2
        A2[nt][r] = e; s += e;
      }
      s += __shfl_xor(s, 16);
      s += __shfl_xor(s, 32);
      const float inv = __builtin_amdgcn_rcpf(s);
      const int colS = (nt*16 + m16) ^ wsw;
      #pragma unroll
      for (int r = 0; r < 4; r++)
        tT[(quad*4 + r)*PITCH + colS] = (_Float16)(A2[nt][r]*inv);
    }
    lds_fence();
    // A-layout attn for the res0 reduce: lane m16 = neighbor row, cols quad*8..
    const half8 Aa0 = *(const half8*)&tT[m16*PITCH + swz];
    const half8 Aa1 = *(const half8*)&tT[m16*PITCH + 32 + swz];

    // ---- attn store: nontemporal, each instruction covers a contiguous aligned
    //      1KB (lane l -> base + s*1024 + l*16) = 8 full 128B lines -> zero RMW,
    //      zero L2 pollution (K/V/Q/xyz stay resident) ----
    {
      float* ap = attn_out + (size_t)gpt*(KNN_*64);
      #pragma unroll
      for (int s = 0; s < 4; s++){
        const int row   = s*4 + quad;                    // row>>2 == s -> swizzle s<<3
        const int colS0 = (m16*4) ^ (s << 3);
        const half4 h = *(const half4*)&tT[row*PITCH + colS0];
        floatx4 o = {(float)h[0], (float)h[1], (float)h[2], (float)h[3]};
        __builtin_nontemporal_store(o, (floatx4*)(ap + s*256 + lane*4));
      }
    }

    // ---- res0 = sum_k attn*(v+P): A-layout product, shfl-reduce over 16 rows ----
    float w0[8], w1[8];
    #pragma unroll
    for (int j = 0; j < 8; j++){
      w0[j] = (float)Aa0[j] * ((float)Va0[j] + (float)Pa0[j]);
      w1[j] = (float)Aa1[j] * ((float)Va1[j] + (float)Pa1[j]);
    }
    #pragma unroll
    for (int mask = 1; mask < 16; mask <<= 1){
      #pragma unroll
      for (int j = 0; j < 8; j++){
        w0[j] += __shfl_xor(w0[j], mask);
        w1[j] += __shfl_xor(w1[j], mask);
      }
    }
    if (m16 == 0){
      half8 o0, o1;
      #pragma unroll
      for (int j = 0; j < 8; j++){ o0[j] = (_Float16)w0[j]; o1[j] = (_Float16)w1[j]; }
      *(half8*)&r0[gpt*64 + quad*8] = o0;
      *(half8*)&r0[gpt*64 + 32 + quad*8] = o1;
    }

    // ---- issue next point's xyz loads (knn result has had a full body to land) ----
    if (p < PPW-1){
      grow_c = grow_n;
      xq0 = xyz[(gpt+1)*3 + 0]; xq1 = xyz[(gpt+1)*3 + 1]; xq2 = xyz[(gpt+1)*3 + 2];
      xn0 = xyz[grow_n*3 + 0];  xn1 = xyz[grow_n*3 + 1];  xn2 = xyz[grow_n*3 + 2];
    }
  }
}

// ---------------- kernel 3: res = res0 @ fc2 + fc2_b + features ----------------
__global__ __launch_bounds__(256, 2) void k3_fc2(
    const _Float16* __restrict__ r0, const float* __restrict__ fc2w,
    const float* __restrict__ fc2b, const float* __restrict__ feat,
    float* __restrict__ out_res)
{
  __shared__ half8 S[512];
  const int tid = threadIdx.x;
  fill_w64(S, fc2w, tid);
  __syncthreads();

  const int wave = tid >> 6, lane = tid & 63, quad = lane >> 4, m16 = lane & 15;
  const int rowbase = blockIdx.x*64 + wave*16;
  float fb[4];
  #pragma unroll
  for (int nt = 0; nt < 4; nt++) fb[nt] = fc2b[nt*16 + m16];

  const half8 A0 = *(const half8*)&r0[(rowbase + m16)*64 + quad*8];
  const half8 A1 = *(const half8*)&r0[(rowbase + m16)*64 + 32 + quad*8];
  const floatx4 z4 = {0.f, 0.f, 0.f, 0.f};

  #pragma unroll
  for (int nt = 0; nt < 4; nt++){
    floatx4 acc = MFMA16(A0, S[nt*64 + lane], z4);
    acc = MFMA16(A1, S[(4 + nt)*64 + lane], acc);
    #pragma unroll
    for (int r = 0; r < 4; r++){
      const int rowg = rowbase + quad*4 + r;
      const int col  = nt*16 + m16;
      out_res[rowg*64 + col] = acc[r] + fb[nt] + feat[rowg*64 + col];
    }
  }
}

extern "C" void kernel_launch(void* const* d_in, const int* in_sizes, int n_in,
                              void* d_out, int out_size, void* d_ws, size_t ws_size,
                              hipStream_t stream)
{
  (void)in_sizes; (void)n_in; (void)out_size; (void)ws_size;
  const float* xyz  = (const float*)d_in[0];
  const float* feat = (const float*)d_in[1];
  const int*   knn  = (const int*)d_in[2];
  const float* fc1w = (const float*)d_in[3];
  const float* fc1b = (const float*)d_in[4];
  const float* fc2w = (const float*)d_in[5];
  const float* fc2b = (const float*)d_in[6];
  const float* d1w  = (const float*)d_in[7];
  const float* d1b  = (const float*)d_in[8];
  const float* d2w  = (const float*)d_in[9];
  const float* d2b  = (const float*)d_in[10];
  const float* g1w  = (const float*)d_in[11];
  const float* g1b  = (const float*)d_in[12];
  const float* g2w  = (const float*)d_in[13];
  const float* g2b  = (const float*)d_in[14];
  const float* wq   = (const float*)d_in[15];
  const float* wk   = (const float*)d_in[16];
  const float* wv   = (const float*)d_in[17];

  _Float16* ws  = (_Float16*)d_ws;
  _Float16* qws = ws;                      // TOT*64 halfs
  _Float16* kws = ws + (size_t)TOT*64;
  _Float16* vws = ws + (size_t)2*TOT*64;
  _Float16* r0  = ws + (size_t)3*TOT*64;

  float* out      = (float*)d_out;
  float* out_res  = out;                     // (B,N,64)
  float* out_attn = out + (size_t)TOT*64;    // (B,N,K,64)

  k1_qkv<<<TOT/64, 256, 0, stream>>>(feat, fc1w, fc1b, wq, wk, wv, qws, kws, vws);
  k2_point<<<TOT/(4*PPW), 256, 0, stream>>>(xyz, knn, d1w, d1b, d2w, d2b,
                                            g1w, g1b, g2w, g2b,
                                            qws, kws, vws, r0, out_attn);
  k3_fc2<<<TOT/64, 256, 0, stream>>>(r0, fc2w, fc2b, feat, out_res);
}

// Round 6
// 302.193 us; speedup vs baseline: 1.0252x; 1.0252x over previous
//
#include <hip/hip_runtime.h>
#include <hip/hip_bf16.h>

#define B_    4
#define N_    8192
#define TOT   (B_*N_)      // 32768 points
#define KNN_  16
#define PPW   8            // points per wave in k2
#define PITCH 80           // LDS tile pitch in halfs (160B, 16B-aligned rows)

typedef _Float16 half8  __attribute__((ext_vector_type(8)));
typedef float    floatx4 __attribute__((ext_vector_type(4)));

#define MFMA16(A, Bv, C) __builtin_amdgcn_mfma_f32_16x16x32_f16((A), (Bv), (C), 0, 0, 0)

__device__ __forceinline__ void lds_fence(){
  asm volatile("s_waitcnt lgkmcnt(0)" ::: "memory");
}
__device__ __forceinline__ half8 h8_load_f32(const float* __restrict__ p){
  float4 a = *(const float4*)p;
  float4 b = *(const float4*)(p + 4);
  half8 r;
  r[0] = (_Float16)a.x; r[1] = (_Float16)a.y; r[2] = (_Float16)a.z; r[3] = (_Float16)a.w;
  r[4] = (_Float16)b.x; r[5] = (_Float16)b.y; r[6] = (_Float16)b.z; r[7] = (_Float16)b.w;
  return r;
}
__device__ __forceinline__ void store8f(float* __restrict__ p, half8 v){
  float4 a = {(float)v[0], (float)v[1], (float)v[2], (float)v[3]};
  float4 b = {(float)v[4], (float)v[5], (float)v[6], (float)v[7]};
  *(float4*)p = a;
  *(float4*)(p + 4) = b;
}

// Fill LDS B-fragment array for a 64x64 row-major f32 weight.
// Layout: frag index (kt*4+nt)*64 + lane; lane holds W[kt*32+quad*8+j][nt*16+(lane&15)].
__device__ void fill_w64(half8* dst, const float* __restrict__ W, int tid){
  for (int i = tid; i < 512; i += 256){
    int lane = i & 63, nt = (i >> 6) & 3, kt = i >> 8;
    int n  = nt*16 + (lane & 15);
    int kb = kt*32 + ((lane >> 4) & 3)*8;
    half8 v;
    #pragma unroll
    for (int j = 0; j < 8; j++) v[j] = (_Float16)W[(kb + j)*64 + n];
    dst[i] = v;
  }
}

// ---------------- kernel 1: x = fc1(features); q/xk/xv = x @ {wq,wk,wv} ----------------
__global__ __launch_bounds__(256, 3) void k1_qkv(
    const float* __restrict__ feat, const float* __restrict__ fc1w, const float* __restrict__ fc1b,
    const float* __restrict__ wqw, const float* __restrict__ wkw, const float* __restrict__ wvw,
    _Float16* __restrict__ qws, _Float16* __restrict__ kws, _Float16* __restrict__ vws)
{
  __shared__ half8 Sfc1[512], Sq[512], Sk[512], Sv[512];
  __shared__ alignas(16) _Float16 xt[4][16*PITCH];
  const int tid = threadIdx.x;
  fill_w64(Sfc1, fc1w, tid);
  fill_w64(Sq, wqw, tid);
  fill_w64(Sk, wkw, tid);
  fill_w64(Sv, wvw, tid);
  __syncthreads();

  const int wave = tid >> 6, lane = tid & 63, quad = lane >> 4, m16 = lane & 15;
  _Float16* tx = &xt[wave][0];
  const int rowbase = blockIdx.x*64 + wave*16;
  float fb[4];
  #pragma unroll
  for (int nt = 0; nt < 4; nt++) fb[nt] = fc1b[nt*16 + m16];

  const int arow = rowbase + m16;
  half8 Fa0 = h8_load_f32(&feat[arow*64 + quad*8]);
  half8 Fa1 = h8_load_f32(&feat[arow*64 + 32 + quad*8]);
  const floatx4 z4 = {0.f, 0.f, 0.f, 0.f};

  #pragma unroll
  for (int nt = 0; nt < 4; nt++){
    floatx4 acc = MFMA16(Fa0, Sfc1[nt*64 + lane], z4);
    acc = MFMA16(Fa1, Sfc1[(4 + nt)*64 + lane], acc);
    const int col = nt*16 + m16;
    #pragma unroll
    for (int r = 0; r < 4; r++)
      tx[(quad*4 + r)*PITCH + col] = (_Float16)(acc[r] + fb[nt]);
  }
  lds_fence();
  const half8 Ax0 = *(const half8*)&tx[m16*PITCH + quad*8];
  const half8 Ax1 = *(const half8*)&tx[m16*PITCH + 32 + quad*8];

#define EMIT_QKV(S, OUT)                                                      \
  { _Pragma("unroll")                                                         \
    for (int nt = 0; nt < 4; nt++){                                           \
      floatx4 acc = MFMA16(Ax0, S[nt*64 + lane], z4);                         \
      acc = MFMA16(Ax1, S[(4 + nt)*64 + lane], acc);                          \
      _Pragma("unroll")                                                       \
      for (int r = 0; r < 4; r++)                                             \
        OUT[(rowbase + quad*4 + r)*64 + nt*16 + m16] = (_Float16)acc[r];      \
    } }
  EMIT_QKV(Sq, qws)
  EMIT_QKV(Sk, kws)
  EMIT_QKV(Sv, vws)
#undef EMIT_QKV
}

// ---------------- kernel 2: per-point fused pos_enc / attention ----------------
__global__ __launch_bounds__(256, 4) void k2_point(
    const float* __restrict__ xyz, const int* __restrict__ knn,
    const float* __restrict__ d1w, const float* __restrict__ d1b,
    const float* __restrict__ d2w, const float* __restrict__ d2b,
    const float* __restrict__ g1w, const float* __restrict__ g1b,
    const float* __restrict__ g2w, const float* __restrict__ g2b,
    const _Float16* __restrict__ qws, const _Float16* __restrict__ kws,
    const _Float16* __restrict__ vws,
    _Float16* __restrict__ r0, float* __restrict__ attn_out)
{
  __shared__ half8 Sd2[512], Sg1[512], Sg2[512];
  __shared__ float4 Td1[64];                       // d1^T columns: {w0,w1,w2,bias}
  // single tile per wave, reused for P (stage2), u (stage3), attn (epilogue).
  // Safe: wave-private + DS ops are in-order within a wave; every read is
  // consumed before the next aliasing write issues (compiler lgkmcnt waits).
  __shared__ alignas(16) _Float16 tiles[4][16*PITCH];
  const int tid = threadIdx.x;
  fill_w64(Sd2, d2w, tid);
  fill_w64(Sg1, g1w, tid);
  fill_w64(Sg2, g2w, tid);
  if (tid < 64)
    Td1[tid] = make_float4(d1w[tid], d1w[64 + tid], d1w[128 + tid], d1b[tid]);
  __syncthreads();

  const int wave = tid >> 6, lane = tid & 63, quad = lane >> 4, m16 = lane & 15;
  _Float16* tT = &tiles[wave][0];

  half8 Fd2[2][4], Fg1[2][4], Fg2[2][4];
  #pragma unroll
  for (int nt = 0; nt < 4; nt++){
    #pragma unroll
    for (int kt = 0; kt < 2; kt++){
      Fd2[kt][nt] = Sd2[(kt*4 + nt)*64 + lane];
      Fg1[kt][nt] = Sg1[(kt*4 + nt)*64 + lane];
      Fg2[kt][nt] = Sg2[(kt*4 + nt)*64 + lane];
    }
  }
  float bd2[4], bg1[4], bg2[4];
  #pragma unroll
  for (int nt = 0; nt < 4; nt++){
    const int c = nt*16 + m16;
    bd2[nt] = d2b[c]; bg1[nt] = g1b[c]; bg2[nt] = g2b[c];
  }
  const floatx4 z4 = {0.f, 0.f, 0.f, 0.f};
  // XOR bank swizzle: write col' = col ^ (quad<<3); read col' = col ^ ((m16>>2)<<3).
  const int wsw = quad << 3;
  const int swz = (quad ^ (m16 >> 2)) << 3;

  // XCD-aware bijective block swizzle: grid = 1024 = 8 XCDs x 128 chunks.
  // Blocks dispatch round-robin over XCDs, so XCD x runs chunks [x*128,(x+1)*128)
  // = one contiguous 4096-point range = HALF A BATCH. Its K/V/xyz gather set is
  // that single batch's (~2.1 MB), which fits the 4 MB per-XCD L2. Without this,
  // all 4 batches run concurrently on every XCD (~8.4 MB/XCD) and every gather
  // misses to HBM (R4/R5: FETCH 310-326 MB vs R0's 46.6 MB).
  const int swb  = (blockIdx.x & 7)*128 + (blockIdx.x >> 3);
  const int gpt0 = swb*(4*PPW) + wave*PPW;          // 32 consecutive points per block
  const int b    = gpt0 >> 13;                      // N=8192; constant within block

  // ---- 1-deep software pipeline for the knn -> xyz gather chain ----
  int grow_c = b*N_ + knn[gpt0*KNN_ + m16];
  float xq0 = xyz[gpt0*3 + 0], xq1 = xyz[gpt0*3 + 1], xq2 = xyz[gpt0*3 + 2];
  float xn0 = xyz[grow_c*3 + 0], xn1 = xyz[grow_c*3 + 1], xn2 = xyz[grow_c*3 + 2];

  for (int p = 0; p < PPW; p++){
    const int gpt  = gpt0 + p;
    const int grow = grow_c;

    // ---- issue all of this point's gathers early, A-layout coalesced (16B/lane) ----
    const half8 Ka0 = *(const half8*)&kws[grow*64 + quad*8];
    const half8 Ka1 = *(const half8*)&kws[grow*64 + 32 + quad*8];
    const half8 Qa0 = *(const half8*)&qws[gpt*64 + quad*8];
    const half8 Qa1 = *(const half8*)&qws[gpt*64 + 32 + quad*8];
    const half8 Va0 = *(const half8*)&vws[grow*64 + quad*8];
    const half8 Va1 = *(const half8*)&vws[grow*64 + 32 + quad*8];

    // prefetch next point's knn row (xyz gather for it is issued at loop bottom)
    int grow_n = 0;
    if (p < PPW-1) grow_n = b*N_ + knn[(gpt+1)*KNN_ + m16];

    const float dx = xq0 - xn0, dy = xq1 - xn1, dz = xq2 - xn2;

    // ---- stage 1: t = relu(rel @ d1 + b), pure VALU, straight into A-layout regs ----
    half8 At0, At1;
    #pragma unroll
    for (int j = 0; j < 8; j++){
      const float4 w  = Td1[quad*8 + j];
      const float4 w2 = Td1[32 + quad*8 + j];
      float t  = fmaf(dx, w.x,  fmaf(dy, w.y,  fmaf(dz, w.z,  w.w)));
      float t2 = fmaf(dx, w2.x, fmaf(dy, w2.y, fmaf(dz, w2.z, w2.w)));
      At0[j] = (_Float16)(t  > 0.f ? t  : 0.f);
      At1[j] = (_Float16)(t2 > 0.f ? t2 : 0.f);
    }

    // ---- stage 2: P = t @ d2 + b -> swizzled tile ----
    #pragma unroll
    for (int nt = 0; nt < 4; nt++){
      floatx4 acc = MFMA16(At0, Fd2[0][nt], z4);
      acc = MFMA16(At1, Fd2[1][nt], acc);
      const int colS = (nt*16 + m16) ^ wsw;
      #pragma unroll
      for (int r = 0; r < 4; r++)
        tT[(quad*4 + r)*PITCH + colS] = (_Float16)(acc[r] + bd2[nt]);
    }
    lds_fence();
    const half8 Pa0 = *(const half8*)&tT[m16*PITCH + swz];
    const half8 Pa1 = *(const half8*)&tT[m16*PITCH + 32 + swz];
    const half8 H0 = Qa0 - Ka0 + Pa0;
    const half8 H1 = Qa1 - Ka1 + Pa1;

    // ---- stage 3: u = relu(H @ g1 + b) -> swizzled tile (reuses tT; in-order DS) ----
    #pragma unroll
    for (int nt = 0; nt < 4; nt++){
      floatx4 acc = MFMA16(H0, Fg1[0][nt], z4);
      acc = MFMA16(H1, Fg1[1][nt], acc);
      const int colS = (nt*16 + m16) ^ wsw;
      #pragma unroll
      for (int r = 0; r < 4; r++){
        float t = acc[r] + bg1[nt];
        tT[(quad*4 + r)*PITCH + colS] = (_Float16)(t > 0.f ? t : 0.f);
      }
    }
    lds_fence();
    const half8 U0 = *(const half8*)&tT[m16*PITCH + swz];
    const half8 U1 = *(const half8*)&tT[m16*PITCH + 32 + swz];

    // ---- stage 4: logits = u @ g2 + b (C layout) ----
    float A2[4][4];
    #pragma unroll
    for (int nt = 0; nt < 4; nt++){
      floatx4 acc = MFMA16(U0, Fg2[0][nt], z4);
      acc = MFMA16(U1, Fg2[1][nt], acc);
      #pragma unroll
      for (int r = 0; r < 4; r++) A2[nt][r] = acc[r] + bg2[nt];
    }

    // ---- softmax over 16 neighbor rows (C layout: 4 local + cross-quad shfls) ----
    #pragma unroll
    for (int nt = 0; nt < 4; nt++){
      float mx = fmaxf(fmaxf(A2[nt][0], A2[nt][1]), fmaxf(A2[nt][2], A2[nt][3]));
      mx = fmaxf(mx, __shfl_xor(mx, 16));
      mx = fmaxf(mx, __shfl_xor(mx, 32));
      float s = 0.f;
      #pragma unroll
      for (int r = 0; r < 4; r++){
        float e = exp2f((A2[nt][r] - mx)*0.18033688011112042f);  // /8, base-2
        A2[nt][r] = e; s += e;
      }
      s += __shfl_xor(s, 16);
      s += __shfl_xor(s, 32);
      const float inv = __builtin_amdgcn_rcpf(s);
      const int colS = (nt*16 + m16) ^ wsw;
      #pragma unroll
      for (int r = 0; r < 4; r++)
        tT[(quad*4 + r)*PITCH + colS] = (_Float16)(A2[nt][r]*inv);
    }
    lds_fence();
    // A-layout attn: lane m16 = neighbor row, cols quad*8.. — contiguous stores.
    const half8 Aa0 = *(const half8*)&tT[m16*PITCH + swz];
    const half8 Aa1 = *(const half8*)&tT[m16*PITCH + 32 + swz];

    // ---- attn store: each instruction covers full 64B sectors (4 lanes x 16B
    //      contiguous per 128B line); wave covers the point's 4KB back-to-back ----
    float* ap = attn_out + ((size_t)gpt*KNN_ + m16)*64;
    store8f(ap + quad*8, Aa0);
    store8f(ap + 32 + quad*8, Aa1);

    // ---- res0 = sum_k attn*(v+P): A-layout product, shfl-reduce over 16 rows ----
    float w0[8], w1[8];
    #pragma unroll
    for (int j = 0; j < 8; j++){
      w0[j] = (float)Aa0[j] * ((float)Va0[j] + (float)Pa0[j]);
      w1[j] = (float)Aa1[j] * ((float)Va1[j] + (float)Pa1[j]);
    }
    #pragma unroll
    for (int mask = 1; mask < 16; mask <<= 1){
      #pragma unroll
      for (int j = 0; j < 8; j++){
        w0[j] += __shfl_xor(w0[j], mask);
        w1[j] += __shfl_xor(w1[j], mask);
      }
    }
    if (m16 == 0){
      half8 o0, o1;
      #pragma unroll
      for (int j = 0; j < 8; j++){ o0[j] = (_Float16)w0[j]; o1[j] = (_Float16)w1[j]; }
      *(half8*)&r0[gpt*64 + quad*8] = o0;
      *(half8*)&r0[gpt*64 + 32 + quad*8] = o1;
    }

    // ---- issue next point's xyz loads (knn result has had a full body to land) ----
    if (p < PPW-1){
      grow_c = grow_n;
      xq0 = xyz[(gpt+1)*3 + 0]; xq1 = xyz[(gpt+1)*3 + 1]; xq2 = xyz[(gpt+1)*3 + 2];
      xn0 = xyz[grow_n*3 + 0];  xn1 = xyz[grow_n*3 + 1];  xn2 = xyz[grow_n*3 + 2];
    }
  }
}

// ---------------- kernel 3: res = res0 @ fc2 + fc2_b + features ----------------
__global__ __launch_bounds__(256, 2) void k3_fc2(
    const _Float16* __restrict__ r0, const float* __restrict__ fc2w,
    const float* __restrict__ fc2b, const float* __restrict__ feat,
    float* __restrict__ out_res)
{
  __shared__ half8 S[512];
  const int tid = threadIdx.x;
  fill_w64(S, fc2w, tid);
  __syncthreads();

  const int wave = tid >> 6, lane = tid & 63, quad = lane >> 4, m16 = lane & 15;
  const int rowbase = blockIdx.x*64 + wave*16;
  float fb[4];
  #pragma unroll
  for (int nt = 0; nt < 4; nt++) fb[nt] = fc2b[nt*16 + m16];

  const half8 A0 = *(const half8*)&r0[(rowbase + m16)*64 + quad*8];
  const half8 A1 = *(const half8*)&r0[(rowbase + m16)*64 + 32 + quad*8];
  const floatx4 z4 = {0.f, 0.f, 0.f, 0.f};

  #pragma unroll
  for (int nt = 0; nt < 4; nt++){
    floatx4 acc = MFMA16(A0, S[nt*64 + lane], z4);
    acc = MFMA16(A1, S[(4 + nt)*64 + lane], acc);
    #pragma unroll
    for (int r = 0; r < 4; r++){
      const int rowg = rowbase + quad*4 + r;
      const int col  = nt*16 + m16;
      out_res[rowg*64 + col] = acc[r] + fb[nt] + feat[rowg*64 + col];
    }
  }
}

extern "C" void kernel_launch(void* const* d_in, const int* in_sizes, int n_in,
                              void* d_out, int out_size, void* d_ws, size_t ws_size,
                              hipStream_t stream)
{
  (void)in_sizes; (void)n_in; (void)out_size; (void)ws_size;
  const float* xyz  = (const float*)d_in[0];
  const float* feat = (const float*)d_in[1];
  const int*   knn  = (const int*)d_in[2];
  const float* fc1w = (const float*)d_in[3];
  const float* fc1b = (const float*)d_in[4];
  const float* fc2w = (const float*)d_in[5];
  const float* fc2b = (const float*)d_in[6];
  const float* d1w  = (const float*)d_in[7];
  const float* d1b  = (const float*)d_in[8];
  const float* d2w  = (const float*)d_in[9];
  const float* d2b  = (const float*)d_in[10];
  const float* g1w  = (const float*)d_in[11];
  const float* g1b  = (const float*)d_in[12];
  const float* g2w  = (const float*)d_in[13];
  const float* g2b  = (const float*)d_in[14];
  const float* wq   = (const float*)d_in[15];
  const float* wk   = (const float*)d_in[16];
  const float* wv   = (const float*)d_in[17];

  _Float16* ws  = (_Float16*)d_ws;
  _Float16* qws = ws;                      // TOT*64 halfs
  _Float16* kws = ws + (size_t)TOT*64;
  _Float16* vws = ws + (size_t)2*TOT*64;
  _Float16* r0  = ws + (size_t)3*TOT*64;

  float* out      = (float*)d_out;
  float* out_res  = out;                     // (B,N,64)
  float* out_attn = out + (size_t)TOT*64;    // (B,N,K,64)

  k1_qkv<<<TOT/64, 256, 0, stream>>>(feat, fc1w, fc1b, wq, wk, wv, qws, kws, vws);
  k2_point<<<TOT/(4*PPW), 256, 0, stream>>>(xyz, knn, d1w, d1b, d2w, d2b,
                                            g1w, g1b, g2w, g2b,
                                            qws, kws, vws, r0, out_attn);
  k3_fc2<<<TOT/64, 256, 0, stream>>>(r0, fc2w, fc2b, feat, out_res);
}

// Round 7
// 258.262 us; speedup vs baseline: 1.1996x; 1.1701x over previous
//
#include <hip/hip_runtime.h>
#include <hip/hip_bf16.h>

#define B_    4
#define N_    8192
#define TOT   (B_*N_)      // 32768 points
#define KNN_  16
#define PPW   8            // points per wave in k2
#define PITCH 80           // LDS tile pitch in halfs (160B, 16B-aligned rows)

typedef _Float16 half8  __attribute__((ext_vector_type(8)));
typedef float    floatx4 __attribute__((ext_vector_type(4)));

#define MFMA16(A, Bv, C) __builtin_amdgcn_mfma_f32_16x16x32_f16((A), (Bv), (C), 0, 0, 0)

__device__ __forceinline__ void lds_fence(){
  asm volatile("s_waitcnt lgkmcnt(0)" ::: "memory");
}
__device__ __forceinline__ half8 h8_load_f32(const float* __restrict__ p){
  float4 a = *(const float4*)p;
  float4 b = *(const float4*)(p + 4);
  half8 r;
  r[0] = (_Float16)a.x; r[1] = (_Float16)a.y; r[2] = (_Float16)a.z; r[3] = (_Float16)a.w;
  r[4] = (_Float16)b.x; r[5] = (_Float16)b.y; r[6] = (_Float16)b.z; r[7] = (_Float16)b.w;
  return r;
}
__device__ __forceinline__ void store8f(float* __restrict__ p, half8 v){
  float4 a = {(float)v[0], (float)v[1], (float)v[2], (float)v[3]};
  float4 b = {(float)v[4], (float)v[5], (float)v[6], (float)v[7]};
  *(float4*)p = a;
  *(float4*)(p + 4) = b;
}

// Fill LDS B-fragment array for a 64x64 row-major f32 weight.
// Layout: frag index (kt*4+nt)*64 + lane; lane holds W[kt*32+quad*8+j][nt*16+(lane&15)].
__device__ void fill_w64(half8* dst, const float* __restrict__ W, int tid){
  for (int i = tid; i < 512; i += 256){
    int lane = i & 63, nt = (i >> 6) & 3, kt = i >> 8;
    int n  = nt*16 + (lane & 15);
    int kb = kt*32 + ((lane >> 4) & 3)*8;
    half8 v;
    #pragma unroll
    for (int j = 0; j < 8; j++) v[j] = (_Float16)W[(kb + j)*64 + n];
    dst[i] = v;
  }
}

// ---------------- kernel 1: x = fc1(features); q/xk/xv = x @ {wq,wk,wv} ----------------
__global__ __launch_bounds__(256, 3) void k1_qkv(
    const float* __restrict__ feat, const float* __restrict__ fc1w, const float* __restrict__ fc1b,
    const float* __restrict__ wqw, const float* __restrict__ wkw, const float* __restrict__ wvw,
    _Float16* __restrict__ qws, _Float16* __restrict__ kws, _Float16* __restrict__ vws)
{
  __shared__ half8 Sfc1[512], Sq[512], Sk[512], Sv[512];
  __shared__ alignas(16) _Float16 xt[4][16*PITCH];
  const int tid = threadIdx.x;
  fill_w64(Sfc1, fc1w, tid);
  fill_w64(Sq, wqw, tid);
  fill_w64(Sk, wkw, tid);
  fill_w64(Sv, wvw, tid);
  __syncthreads();

  const int wave = tid >> 6, lane = tid & 63, quad = lane >> 4, m16 = lane & 15;
  _Float16* tx = &xt[wave][0];
  const int rowbase = blockIdx.x*64 + wave*16;
  float fb[4];
  #pragma unroll
  for (int nt = 0; nt < 4; nt++) fb[nt] = fc1b[nt*16 + m16];

  const int arow = rowbase + m16;
  half8 Fa0 = h8_load_f32(&feat[arow*64 + quad*8]);
  half8 Fa1 = h8_load_f32(&feat[arow*64 + 32 + quad*8]);
  const floatx4 z4 = {0.f, 0.f, 0.f, 0.f};

  #pragma unroll
  for (int nt = 0; nt < 4; nt++){
    floatx4 acc = MFMA16(Fa0, Sfc1[nt*64 + lane], z4);
    acc = MFMA16(Fa1, Sfc1[(4 + nt)*64 + lane], acc);
    const int col = nt*16 + m16;
    #pragma unroll
    for (int r = 0; r < 4; r++)
      tx[(quad*4 + r)*PITCH + col] = (_Float16)(acc[r] + fb[nt]);
  }
  lds_fence();
  const half8 Ax0 = *(const half8*)&tx[m16*PITCH + quad*8];
  const half8 Ax1 = *(const half8*)&tx[m16*PITCH + 32 + quad*8];

#define EMIT_QKV(S, OUT)                                                      \
  { _Pragma("unroll")                                                         \
    for (int nt = 0; nt < 4; nt++){                                           \
      floatx4 acc = MFMA16(Ax0, S[nt*64 + lane], z4);                         \
      acc = MFMA16(Ax1, S[(4 + nt)*64 + lane], acc);                          \
      _Pragma("unroll")                                                       \
      for (int r = 0; r < 4; r++)                                             \
        OUT[(rowbase + quad*4 + r)*64 + nt*16 + m16] = (_Float16)acc[r];      \
    } }
  EMIT_QKV(Sq, qws)
  EMIT_QKV(Sk, kws)
  EMIT_QKV(Sv, vws)
#undef EMIT_QKV
}

// ---------------- kernel 2: per-point fused pos_enc / attention ----------------
// A/B vs round 6: ONLY change is __launch_bounds__ 4 -> 2 (occupancy causality test).
__global__ __launch_bounds__(256, 2) void k2_point(
    const float* __restrict__ xyz, const int* __restrict__ knn,
    const float* __restrict__ d1w, const float* __restrict__ d1b,
    const float* __restrict__ d2w, const float* __restrict__ d2b,
    const float* __restrict__ g1w, const float* __restrict__ g1b,
    const float* __restrict__ g2w, const float* __restrict__ g2b,
    const _Float16* __restrict__ qws, const _Float16* __restrict__ kws,
    const _Float16* __restrict__ vws,
    _Float16* __restrict__ r0, float* __restrict__ attn_out)
{
  __shared__ half8 Sd2[512], Sg1[512], Sg2[512];
  __shared__ float4 Td1[64];                       // d1^T columns: {w0,w1,w2,bias}
  // single tile per wave, reused for P (stage2), u (stage3), attn (epilogue).
  // Safe: wave-private + DS ops are in-order within a wave; every read is
  // consumed before the next aliasing write issues (compiler lgkmcnt waits).
  __shared__ alignas(16) _Float16 tiles[4][16*PITCH];
  const int tid = threadIdx.x;
  fill_w64(Sd2, d2w, tid);
  fill_w64(Sg1, g1w, tid);
  fill_w64(Sg2, g2w, tid);
  if (tid < 64)
    Td1[tid] = make_float4(d1w[tid], d1w[64 + tid], d1w[128 + tid], d1b[tid]);
  __syncthreads();

  const int wave = tid >> 6, lane = tid & 63, quad = lane >> 4, m16 = lane & 15;
  _Float16* tT = &tiles[wave][0];

  half8 Fd2[2][4], Fg1[2][4], Fg2[2][4];
  #pragma unroll
  for (int nt = 0; nt < 4; nt++){
    #pragma unroll
    for (int kt = 0; kt < 2; kt++){
      Fd2[kt][nt] = Sd2[(kt*4 + nt)*64 + lane];
      Fg1[kt][nt] = Sg1[(kt*4 + nt)*64 + lane];
      Fg2[kt][nt] = Sg2[(kt*4 + nt)*64 + lane];
    }
  }
  float bd2[4], bg1[4], bg2[4];
  #pragma unroll
  for (int nt = 0; nt < 4; nt++){
    const int c = nt*16 + m16;
    bd2[nt] = d2b[c]; bg1[nt] = g1b[c]; bg2[nt] = g2b[c];
  }
  const floatx4 z4 = {0.f, 0.f, 0.f, 0.f};
  // XOR bank swizzle: write col' = col ^ (quad<<3); read col' = col ^ ((m16>>2)<<3).
  const int wsw = quad << 3;
  const int swz = (quad ^ (m16 >> 2)) << 3;

  // XCD-aware bijective block swizzle (kept from R6; cost-free, mildly positive).
  const int swb  = (blockIdx.x & 7)*128 + (blockIdx.x >> 3);
  const int gpt0 = swb*(4*PPW) + wave*PPW;          // 32 consecutive points per block
  const int b    = gpt0 >> 13;                      // N=8192; constant within block

  // ---- 1-deep software pipeline for the knn -> xyz gather chain ----
  int grow_c = b*N_ + knn[gpt0*KNN_ + m16];
  float xq0 = xyz[gpt0*3 + 0], xq1 = xyz[gpt0*3 + 1], xq2 = xyz[gpt0*3 + 2];
  float xn0 = xyz[grow_c*3 + 0], xn1 = xyz[grow_c*3 + 1], xn2 = xyz[grow_c*3 + 2];

  for (int p = 0; p < PPW; p++){
    const int gpt  = gpt0 + p;
    const int grow = grow_c;

    // ---- issue all of this point's gathers early, A-layout coalesced (16B/lane) ----
    const half8 Ka0 = *(const half8*)&kws[grow*64 + quad*8];
    const half8 Ka1 = *(const half8*)&kws[grow*64 + 32 + quad*8];
    const half8 Qa0 = *(const half8*)&qws[gpt*64 + quad*8];
    const half8 Qa1 = *(const half8*)&qws[gpt*64 + 32 + quad*8];
    const half8 Va0 = *(const half8*)&vws[grow*64 + quad*8];
    const half8 Va1 = *(const half8*)&vws[grow*64 + 32 + quad*8];

    // prefetch next point's knn row (xyz gather for it is issued at loop bottom)
    int grow_n = 0;
    if (p < PPW-1) grow_n = b*N_ + knn[(gpt+1)*KNN_ + m16];

    const float dx = xq0 - xn0, dy = xq1 - xn1, dz = xq2 - xn2;

    // ---- stage 1: t = relu(rel @ d1 + b), pure VALU, straight into A-layout regs ----
    half8 At0, At1;
    #pragma unroll
    for (int j = 0; j < 8; j++){
      const float4 w  = Td1[quad*8 + j];
      const float4 w2 = Td1[32 + quad*8 + j];
      float t  = fmaf(dx, w.x,  fmaf(dy, w.y,  fmaf(dz, w.z,  w.w)));
      float t2 = fmaf(dx, w2.x, fmaf(dy, w2.y, fmaf(dz, w2.z, w2.w)));
      At0[j] = (_Float16)(t  > 0.f ? t  : 0.f);
      At1[j] = (_Float16)(t2 > 0.f ? t2 : 0.f);
    }

    // ---- stage 2: P = t @ d2 + b -> swizzled tile ----
    #pragma unroll
    for (int nt = 0; nt < 4; nt++){
      floatx4 acc = MFMA16(At0, Fd2[0][nt], z4);
      acc = MFMA16(At1, Fd2[1][nt], acc);
      const int colS = (nt*16 + m16) ^ wsw;
      #pragma unroll
      for (int r = 0; r < 4; r++)
        tT[(quad*4 + r)*PITCH + colS] = (_Float16)(acc[r] + bd2[nt]);
    }
    lds_fence();
    const half8 Pa0 = *(const half8*)&tT[m16*PITCH + swz];
    const half8 Pa1 = *(const half8*)&tT[m16*PITCH + 32 + swz];
    const half8 H0 = Qa0 - Ka0 + Pa0;
    const half8 H1 = Qa1 - Ka1 + Pa1;

    // ---- stage 3: u = relu(H @ g1 + b) -> swizzled tile (reuses tT; in-order DS) ----
    #pragma unroll
    for (int nt = 0; nt < 4; nt++){
      floatx4 acc = MFMA16(H0, Fg1[0][nt], z4);
      acc = MFMA16(H1, Fg1[1][nt], acc);
      const int colS = (nt*16 + m16) ^ wsw;
      #pragma unroll
      for (int r = 0; r < 4; r++){
        float t = acc[r] + bg1[nt];
        tT[(quad*4 + r)*PITCH + colS] = (_Float16)(t > 0.f ? t : 0.f);
      }
    }
    lds_fence();
    const half8 U0 = *(const half8*)&tT[m16*PITCH + swz];
    const half8 U1 = *(const half8*)&tT[m16*PITCH + 32 + swz];

    // ---- stage 4: logits = u @ g2 + b (C layout) ----
    float A2[4][4];
    #pragma unroll
    for (int nt = 0; nt < 4; nt++){
      floatx4 acc = MFMA16(U0, Fg2[0][nt], z4);
      acc = MFMA16(U1, Fg2[1][nt], acc);
      #pragma unroll
      for (int r = 0; r < 4; r++) A2[nt][r] = acc[r] + bg2[nt];
    }

    // ---- softmax over 16 neighbor rows (C layout: 4 local + cross-quad shfls) ----
    #pragma unroll
    for (int nt = 0; nt < 4; nt++){
      float mx = fmaxf(fmaxf(A2[nt][0], A2[nt][1]), fmaxf(A2[nt][2], A2[nt][3]));
      mx = fmaxf(mx, __shfl_xor(mx, 16));
      mx = fmaxf(mx, __shfl_xor(mx, 32));
      float s = 0.f;
      #pragma unroll
      for (int r = 0; r < 4; r++){
        float e = exp2f((A2[nt][r] - mx)*0.18033688011112042f);  // /8, base-2
        A2[nt][r] = e; s += e;
      }
      s += __shfl_xor(s, 16);
      s += __shfl_xor(s, 32);
      const float inv = __builtin_amdgcn_rcpf(s);
      const int colS = (nt*16 + m16) ^ wsw;
      #pragma unroll
      for (int r = 0; r < 4; r++)
        tT[(quad*4 + r)*PITCH + colS] = (_Float16)(A2[nt][r]*inv);
    }
    lds_fence();
    // A-layout attn: lane m16 = neighbor row, cols quad*8.. — contiguous stores.
    const half8 Aa0 = *(const half8*)&tT[m16*PITCH + swz];
    const half8 Aa1 = *(const half8*)&tT[m16*PITCH + 32 + swz];

    // ---- attn store: full-sector f32 stores, wave covers the point's 4KB ----
    float* ap = attn_out + ((size_t)gpt*KNN_ + m16)*64;
    store8f(ap + quad*8, Aa0);
    store8f(ap + 32 + quad*8, Aa1);

    // ---- res0 = sum_k attn*(v+P): A-layout product, shfl-reduce over 16 rows ----
    float w0[8], w1[8];
    #pragma unroll
    for (int j = 0; j < 8; j++){
      w0[j] = (float)Aa0[j] * ((float)Va0[j] + (float)Pa0[j]);
      w1[j] = (float)Aa1[j] * ((float)Va1[j] + (float)Pa1[j]);
    }
    #pragma unroll
    for (int mask = 1; mask < 16; mask <<= 1){
      #pragma unroll
      for (int j = 0; j < 8; j++){
        w0[j] += __shfl_xor(w0[j], mask);
        w1[j] += __shfl_xor(w1[j], mask);
      }
    }
    if (m16 == 0){
      half8 o0, o1;
      #pragma unroll
      for (int j = 0; j < 8; j++){ o0[j] = (_Float16)w0[j]; o1[j] = (_Float16)w1[j]; }
      *(half8*)&r0[gpt*64 + quad*8] = o0;
      *(half8*)&r0[gpt*64 + 32 + quad*8] = o1;
    }

    // ---- issue next point's xyz loads (knn result has had a full body to land) ----
    if (p < PPW-1){
      grow_c = grow_n;
      xq0 = xyz[(gpt+1)*3 + 0]; xq1 = xyz[(gpt+1)*3 + 1]; xq2 = xyz[(gpt+1)*3 + 2];
      xn0 = xyz[grow_n*3 + 0];  xn1 = xyz[grow_n*3 + 1];  xn2 = xyz[grow_n*3 + 2];
    }
  }
}

// ---------------- kernel 3: res = res0 @ fc2 + fc2_b + features ----------------
__global__ __launch_bounds__(256, 2) void k3_fc2(
    const _Float16* __restrict__ r0, const float* __restrict__ fc2w,
    const float* __restrict__ fc2b, const float* __restrict__ feat,
    float* __restrict__ out_res)
{
  __shared__ half8 S[512];
  const int tid = threadIdx.x;
  fill_w64(S, fc2w, tid);
  __syncthreads();

  const int wave = tid >> 6, lane = tid & 63, quad = lane >> 4, m16 = lane & 15;
  const int rowbase = blockIdx.x*64 + wave*16;
  float fb[4];
  #pragma unroll
  for (int nt = 0; nt < 4; nt++) fb[nt] = fc2b[nt*16 + m16];

  const half8 A0 = *(const half8*)&r0[(rowbase + m16)*64 + quad*8];
  const half8 A1 = *(const half8*)&r0[(rowbase + m16)*64 + 32 + quad*8];
  const floatx4 z4 = {0.f, 0.f, 0.f, 0.f};

  #pragma unroll
  for (int nt = 0; nt < 4; nt++){
    floatx4 acc = MFMA16(A0, S[nt*64 + lane], z4);
    acc = MFMA16(A1, S[(4 + nt)*64 + lane], acc);
    #pragma unroll
    for (int r = 0; r < 4; r++){
      const int rowg = rowbase + quad*4 + r;
      const int col  = nt*16 + m16;
      out_res[rowg*64 + col] = acc[r] + fb[nt] + feat[rowg*64 + col];
    }
  }
}

extern "C" void kernel_launch(void* const* d_in, const int* in_sizes, int n_in,
                              void* d_out, int out_size, void* d_ws, size_t ws_size,
                              hipStream_t stream)
{
  (void)in_sizes; (void)n_in; (void)out_size; (void)ws_size;
  const float* xyz  = (const float*)d_in[0];
  const float* feat = (const float*)d_in[1];
  const int*   knn  = (const int*)d_in[2];
  const float* fc1w = (const float*)d_in[3];
  const float* fc1b = (const float*)d_in[4];
  const float* fc2w = (const float*)d_in[5];
  const float* fc2b = (const float*)d_in[6];
  const float* d1w  = (const float*)d_in[7];
  const float* d1b  = (const float*)d_in[8];
  const float* d2w  = (const float*)d_in[9];
  const float* d2b  = (const float*)d_in[10];
  const float* g1w  = (const float*)d_in[11];
  const float* g1b  = (const float*)d_in[12];
  const float* g2w  = (const float*)d_in[13];
  const float* g2b  = (const float*)d_in[14];
  const float* wq   = (const float*)d_in[15];
  const float* wk   = (const float*)d_in[16];
  const float* wv   = (const float*)d_in[17];

  _Float16* ws  = (_Float16*)d_ws;
  _Float16* qws = ws;                      // TOT*64 halfs
  _Float16* kws = ws + (size_t)TOT*64;
  _Float16* vws = ws + (size_t)2*TOT*64;
  _Float16* r0  = ws + (size_t)3*TOT*64;

  float* out      = (float*)d_out;
  float* out_res  = out;                     // (B,N,64)
  float* out_attn = out + (size_t)TOT*64;    // (B,N,K,64)

  k1_qkv<<<TOT/64, 256, 0, stream>>>(feat, fc1w, fc1b, wq, wk, wv, qws, kws, vws);
  k2_point<<<TOT/(4*PPW), 256, 0, stream>>>(xyz, knn, d1w, d1b, d2w, d2b,
                                            g1w, g1b, g2w, g2b,
                                            qws, kws, vws, r0, out_attn);
  k3_fc2<<<TOT/64, 256, 0, stream>>>(r0, fc2w, fc2b, feat, out_res);
}

// Round 8
// 255.379 us; speedup vs baseline: 1.2131x; 1.0113x over previous
//
#include <hip/hip_runtime.h>
#include <hip/hip_bf16.h>

#define B_    4
#define N_    8192
#define TOT   (B_*N_)      // 32768 points
#define KNN_  16
#define PPW   8            // points per wave in k2
#define PITCH 80           // LDS tile pitch in halfs (160B, 16B-aligned rows)

typedef _Float16 half8  __attribute__((ext_vector_type(8)));
typedef float    floatx4 __attribute__((ext_vector_type(4)));

#define MFMA16(A, Bv, C) __builtin_amdgcn_mfma_f32_16x16x32_f16((A), (Bv), (C), 0, 0, 0)

__device__ __forceinline__ void lds_fence(){
  asm volatile("s_waitcnt lgkmcnt(0)" ::: "memory");
}
__device__ __forceinline__ half8 h8_load_f32(const float* __restrict__ p){
  float4 a = *(const float4*)p;
  float4 b = *(const float4*)(p + 4);
  half8 r;
  r[0] = (_Float16)a.x; r[1] = (_Float16)a.y; r[2] = (_Float16)a.z; r[3] = (_Float16)a.w;
  r[4] = (_Float16)b.x; r[5] = (_Float16)b.y; r[6] = (_Float16)b.z; r[7] = (_Float16)b.w;
  return r;
}
__device__ __forceinline__ void store8f(float* __restrict__ p, half8 v){
  float4 a = {(float)v[0], (float)v[1], (float)v[2], (float)v[3]};
  float4 b = {(float)v[4], (float)v[5], (float)v[6], (float)v[7]};
  *(float4*)p = a;
  *(float4*)(p + 4) = b;
}

// Fill LDS B-fragment array for a 64x64 row-major f32 weight.
// Layout: frag index (kt*4+nt)*64 + lane; lane holds W[kt*32+quad*8+j][nt*16+(lane&15)].
__device__ void fill_w64(half8* dst, const float* __restrict__ W, int tid){
  for (int i = tid; i < 512; i += 256){
    int lane = i & 63, nt = (i >> 6) & 3, kt = i >> 8;
    int n  = nt*16 + (lane & 15);
    int kb = kt*32 + ((lane >> 4) & 3)*8;
    half8 v;
    #pragma unroll
    for (int j = 0; j < 8; j++) v[j] = (_Float16)W[(kb + j)*64 + n];
    dst[i] = v;
  }
}

// ---------------- kernel 1: x = fc1(features); q/xk/xv = x @ {wq,wk,wv} ----------------
__global__ __launch_bounds__(256, 3) void k1_qkv(
    const float* __restrict__ feat, const float* __restrict__ fc1w, const float* __restrict__ fc1b,
    const float* __restrict__ wqw, const float* __restrict__ wkw, const float* __restrict__ wvw,
    _Float16* __restrict__ qws, _Float16* __restrict__ kws, _Float16* __restrict__ vws)
{
  __shared__ half8 Sfc1[512], Sq[512], Sk[512], Sv[512];
  __shared__ alignas(16) _Float16 xt[4][16*PITCH];
  const int tid = threadIdx.x;
  fill_w64(Sfc1, fc1w, tid);
  fill_w64(Sq, wqw, tid);
  fill_w64(Sk, wkw, tid);
  fill_w64(Sv, wvw, tid);
  __syncthreads();

  const int wave = tid >> 6, lane = tid & 63, quad = lane >> 4, m16 = lane & 15;
  _Float16* tx = &xt[wave][0];
  const int rowbase = blockIdx.x*64 + wave*16;
  float fb[4];
  #pragma unroll
  for (int nt = 0; nt < 4; nt++) fb[nt] = fc1b[nt*16 + m16];

  const int arow = rowbase + m16;
  half8 Fa0 = h8_load_f32(&feat[arow*64 + quad*8]);
  half8 Fa1 = h8_load_f32(&feat[arow*64 + 32 + quad*8]);
  const floatx4 z4 = {0.f, 0.f, 0.f, 0.f};

  #pragma unroll
  for (int nt = 0; nt < 4; nt++){
    floatx4 acc = MFMA16(Fa0, Sfc1[nt*64 + lane], z4);
    acc = MFMA16(Fa1, Sfc1[(4 + nt)*64 + lane], acc);
    const int col = nt*16 + m16;
    #pragma unroll
    for (int r = 0; r < 4; r++)
      tx[(quad*4 + r)*PITCH + col] = (_Float16)(acc[r] + fb[nt]);
  }
  lds_fence();
  const half8 Ax0 = *(const half8*)&tx[m16*PITCH + quad*8];
  const half8 Ax1 = *(const half8*)&tx[m16*PITCH + 32 + quad*8];

#define EMIT_QKV(S, OUT)                                                      \
  { _Pragma("unroll")                                                         \
    for (int nt = 0; nt < 4; nt++){                                           \
      floatx4 acc = MFMA16(Ax0, S[nt*64 + lane], z4);                         \
      acc = MFMA16(Ax1, S[(4 + nt)*64 + lane], acc);                          \
      _Pragma("unroll")                                                       \
      for (int r = 0; r < 4; r++)                                             \
        OUT[(rowbase + quad*4 + r)*64 + nt*16 + m16] = (_Float16)acc[r];      \
    } }
  EMIT_QKV(Sq, qws)
  EMIT_QKV(Sk, kws)
  EMIT_QKV(Sv, vws)
#undef EMIT_QKV
}

// ---------------- kernel 2: per-point fused pos_enc / attention ----------------
// vs round 7: 2-point software pipeline (two wave-private tiles T0/T1), halves
// the lgkmcnt(0) fence count per point and doubles independent work per fence.
__global__ __launch_bounds__(256, 2) void k2_point(
    const float* __restrict__ xyz, const int* __restrict__ knn,
    const float* __restrict__ d1w, const float* __restrict__ d1b,
    const float* __restrict__ d2w, const float* __restrict__ d2b,
    const float* __restrict__ g1w, const float* __restrict__ g1b,
    const float* __restrict__ g2w, const float* __restrict__ g2b,
    const _Float16* __restrict__ qws, const _Float16* __restrict__ kws,
    const _Float16* __restrict__ vws,
    _Float16* __restrict__ r0, float* __restrict__ attn_out)
{
  __shared__ half8 Sd2[512], Sg1[512], Sg2[512];
  __shared__ float4 Td1[64];                       // d1^T columns: {w0,w1,w2,bias}
  __shared__ alignas(16) _Float16 tiles[4][2][16*PITCH];   // 2 tiles per wave
  const int tid = threadIdx.x;
  fill_w64(Sd2, d2w, tid);
  fill_w64(Sg1, g1w, tid);
  fill_w64(Sg2, g2w, tid);
  if (tid < 64)
    Td1[tid] = make_float4(d1w[tid], d1w[64 + tid], d1w[128 + tid], d1b[tid]);
  __syncthreads();

  const int wave = tid >> 6, lane = tid & 63, quad = lane >> 4, m16 = lane & 15;
  _Float16* tT0 = &tiles[wave][0][0];
  _Float16* tT1 = &tiles[wave][1][0];

  half8 Fd2[2][4], Fg1[2][4], Fg2[2][4];
  #pragma unroll
  for (int nt = 0; nt < 4; nt++){
    #pragma unroll
    for (int kt = 0; kt < 2; kt++){
      Fd2[kt][nt] = Sd2[(kt*4 + nt)*64 + lane];
      Fg1[kt][nt] = Sg1[(kt*4 + nt)*64 + lane];
      Fg2[kt][nt] = Sg2[(kt*4 + nt)*64 + lane];
    }
  }
  float bd2[4], bg1[4], bg2[4];
  #pragma unroll
  for (int nt = 0; nt < 4; nt++){
    const int c = nt*16 + m16;
    bd2[nt] = d2b[c]; bg1[nt] = g1b[c]; bg2[nt] = g2b[c];
  }
  const floatx4 z4 = {0.f, 0.f, 0.f, 0.f};
  // XOR bank swizzle: write col' = col ^ (quad<<3); read col' = col ^ ((m16>>2)<<3).
  const int wsw = quad << 3;
  const int swz = (quad ^ (m16 >> 2)) << 3;

  // XCD-aware bijective block swizzle (grid 1024 = 8 XCDs x 128 chunks).
  const int swb  = (blockIdx.x & 7)*128 + (blockIdx.x >> 3);
  const int gpt0 = swb*(4*PPW) + wave*PPW;          // 32 consecutive points per block
  const int b    = gpt0 >> 13;                      // N=8192; constant within block

  // ---- pair-deep pipeline for the knn -> xyz gather chain ----
  int growA = b*N_ + knn[gpt0*KNN_ + m16];
  int growB = b*N_ + knn[(gpt0+1)*KNN_ + m16];
  float xqA0 = xyz[gpt0*3+0],     xqA1 = xyz[gpt0*3+1],     xqA2 = xyz[gpt0*3+2];
  float xqB0 = xyz[(gpt0+1)*3+0], xqB1 = xyz[(gpt0+1)*3+1], xqB2 = xyz[(gpt0+1)*3+2];
  float xnA0 = xyz[growA*3+0], xnA1 = xyz[growA*3+1], xnA2 = xyz[growA*3+2];
  float xnB0 = xyz[growB*3+0], xnB1 = xyz[growB*3+1], xnB2 = xyz[growB*3+2];

  for (int pp = 0; pp < PPW; pp += 2){
    const int gptA = gpt0 + pp, gptB = gptA + 1;
    const int gA = growA, gB = growB;

    // ---- gathers for BOTH points, A-layout coalesced (16B/lane) ----
    const half8 KaA0 = *(const half8*)&kws[gA*64 + quad*8];
    const half8 KaA1 = *(const half8*)&kws[gA*64 + 32 + quad*8];
    const half8 QaA0 = *(const half8*)&qws[gptA*64 + quad*8];
    const half8 QaA1 = *(const half8*)&qws[gptA*64 + 32 + quad*8];
    const half8 VaA0 = *(const half8*)&vws[gA*64 + quad*8];
    const half8 VaA1 = *(const half8*)&vws[gA*64 + 32 + quad*8];
    const half8 KaB0 = *(const half8*)&kws[gB*64 + quad*8];
    const half8 KaB1 = *(const half8*)&kws[gB*64 + 32 + quad*8];
    const half8 QaB0 = *(const half8*)&qws[gptB*64 + quad*8];
    const half8 QaB1 = *(const half8*)&qws[gptB*64 + 32 + quad*8];
    const half8 VaB0 = *(const half8*)&vws[gB*64 + quad*8];
    const half8 VaB1 = *(const half8*)&vws[gB*64 + 32 + quad*8];

    // prefetch next pair's knn rows
    int growA_n = 0, growB_n = 0;
    if (pp < PPW-2){
      growA_n = b*N_ + knn[(gptA+2)*KNN_ + m16];
      growB_n = b*N_ + knn[(gptB+2)*KNN_ + m16];
    }

    const float dxA = xqA0 - xnA0, dyA = xqA1 - xnA1, dzA = xqA2 - xnA2;
    const float dxB = xqB0 - xnB0, dyB = xqB1 - xnB1, dzB = xqB2 - xnB2;

    // ---- stage 1 (both): t = relu(rel @ d1 + b), pure VALU ----
    half8 AtA0, AtA1, AtB0, AtB1;
    #pragma unroll
    for (int j = 0; j < 8; j++){
      const float4 w  = Td1[quad*8 + j];
      const float4 w2 = Td1[32 + quad*8 + j];
      float tA  = fmaf(dxA, w.x,  fmaf(dyA, w.y,  fmaf(dzA, w.z,  w.w)));
      float tA2 = fmaf(dxA, w2.x, fmaf(dyA, w2.y, fmaf(dzA, w2.z, w2.w)));
      float tB  = fmaf(dxB, w.x,  fmaf(dyB, w.y,  fmaf(dzB, w.z,  w.w)));
      float tB2 = fmaf(dxB, w2.x, fmaf(dyB, w2.y, fmaf(dzB, w2.z, w2.w)));
      AtA0[j] = (_Float16)(tA  > 0.f ? tA  : 0.f);
      AtA1[j] = (_Float16)(tA2 > 0.f ? tA2 : 0.f);
      AtB0[j] = (_Float16)(tB  > 0.f ? tB  : 0.f);
      AtB1[j] = (_Float16)(tB2 > 0.f ? tB2 : 0.f);
    }

    // ---- stage 2 (both): P = t @ d2 + b -> T0 / T1 ----
    #pragma unroll
    for (int nt = 0; nt < 4; nt++){
      floatx4 accA = MFMA16(AtA0, Fd2[0][nt], z4);
      accA = MFMA16(AtA1, Fd2[1][nt], accA);
      floatx4 accB = MFMA16(AtB0, Fd2[0][nt], z4);
      accB = MFMA16(AtB1, Fd2[1][nt], accB);
      const int colS = (nt*16 + m16) ^ wsw;
      #pragma unroll
      for (int r = 0; r < 4; r++){
        tT0[(quad*4 + r)*PITCH + colS] = (_Float16)(accA[r] + bd2[nt]);
        tT1[(quad*4 + r)*PITCH + colS] = (_Float16)(accB[r] + bd2[nt]);
      }
    }
    lds_fence();                                            // fence 1 (shared)
    const half8 PaA0 = *(const half8*)&tT0[m16*PITCH + swz];
    const half8 PaA1 = *(const half8*)&tT0[m16*PITCH + 32 + swz];
    const half8 PaB0 = *(const half8*)&tT1[m16*PITCH + swz];
    const half8 PaB1 = *(const half8*)&tT1[m16*PITCH + 32 + swz];
    const half8 HA0 = QaA0 - KaA0 + PaA0;
    const half8 HA1 = QaA1 - KaA1 + PaA1;
    const half8 HB0 = QaB0 - KaB0 + PaB0;
    const half8 HB1 = QaB1 - KaB1 + PaB1;

    // ---- stage 3 (both): u = relu(H @ g1 + b) -> T0 / T1 ----
    #pragma unroll
    for (int nt = 0; nt < 4; nt++){
      floatx4 accA = MFMA16(HA0, Fg1[0][nt], z4);
      accA = MFMA16(HA1, Fg1[1][nt], accA);
      floatx4 accB = MFMA16(HB0, Fg1[0][nt], z4);
      accB = MFMA16(HB1, Fg1[1][nt], accB);
      const int colS = (nt*16 + m16) ^ wsw;
      #pragma unroll
      for (int r = 0; r < 4; r++){
        float tA = accA[r] + bg1[nt];
        float tB = accB[r] + bg1[nt];
        tT0[(quad*4 + r)*PITCH + colS] = (_Float16)(tA > 0.f ? tA : 0.f);
        tT1[(quad*4 + r)*PITCH + colS] = (_Float16)(tB > 0.f ? tB : 0.f);
      }
    }
    lds_fence();                                            // fence 2 (shared)
    const half8 UA0 = *(const half8*)&tT0[m16*PITCH + swz];
    const half8 UA1 = *(const half8*)&tT0[m16*PITCH + 32 + swz];
    const half8 UB0 = *(const half8*)&tT1[m16*PITCH + swz];
    const half8 UB1 = *(const half8*)&tT1[m16*PITCH + 32 + swz];

    // ---- stage 4 (both): logits = u @ g2 + b, softmax in C layout ----
    float A2A[4][4], A2B[4][4];
    #pragma unroll
    for (int nt = 0; nt < 4; nt++){
      floatx4 accA = MFMA16(UA0, Fg2[0][nt], z4);
      accA = MFMA16(UA1, Fg2[1][nt], accA);
      floatx4 accB = MFMA16(UB0, Fg2[0][nt], z4);
      accB = MFMA16(UB1, Fg2[1][nt], accB);
      #pragma unroll
      for (int r = 0; r < 4; r++){ A2A[nt][r] = accA[r] + bg2[nt]; A2B[nt][r] = accB[r] + bg2[nt]; }
    }
    #pragma unroll
    for (int nt = 0; nt < 4; nt++){
      float mxA = fmaxf(fmaxf(A2A[nt][0], A2A[nt][1]), fmaxf(A2A[nt][2], A2A[nt][3]));
      float mxB = fmaxf(fmaxf(A2B[nt][0], A2B[nt][1]), fmaxf(A2B[nt][2], A2B[nt][3]));
      mxA = fmaxf(mxA, __shfl_xor(mxA, 16));
      mxB = fmaxf(mxB, __shfl_xor(mxB, 16));
      mxA = fmaxf(mxA, __shfl_xor(mxA, 32));
      mxB = fmaxf(mxB, __shfl_xor(mxB, 32));
      float sA = 0.f, sB = 0.f;
      #pragma unroll
      for (int r = 0; r < 4; r++){
        float eA = exp2f((A2A[nt][r] - mxA)*0.18033688011112042f);  // /8, base-2
        float eB = exp2f((A2B[nt][r] - mxB)*0.18033688011112042f);
        A2A[nt][r] = eA; sA += eA;
        A2B[nt][r] = eB; sB += eB;
      }
      sA += __shfl_xor(sA, 16);
      sB += __shfl_xor(sB, 16);
      sA += __shfl_xor(sA, 32);
      sB += __shfl_xor(sB, 32);
      const float invA = __builtin_amdgcn_rcpf(sA);
      const float invB = __builtin_amdgcn_rcpf(sB);
      const int colS = (nt*16 + m16) ^ wsw;
      #pragma unroll
      for (int r = 0; r < 4; r++){
        tT0[(quad*4 + r)*PITCH + colS] = (_Float16)(A2A[nt][r]*invA);
        tT1[(quad*4 + r)*PITCH + colS] = (_Float16)(A2B[nt][r]*invB);
      }
    }
    lds_fence();                                            // fence 3 (shared)
    const half8 AaA0 = *(const half8*)&tT0[m16*PITCH + swz];
    const half8 AaA1 = *(const half8*)&tT0[m16*PITCH + 32 + swz];
    const half8 AaB0 = *(const half8*)&tT1[m16*PITCH + swz];
    const half8 AaB1 = *(const half8*)&tT1[m16*PITCH + 32 + swz];

    // ---- attn stores: full-sector f32, wave covers each point's 4KB ----
    float* apA = attn_out + ((size_t)gptA*KNN_ + m16)*64;
    store8f(apA + quad*8, AaA0);
    store8f(apA + 32 + quad*8, AaA1);
    float* apB = attn_out + ((size_t)gptB*KNN_ + m16)*64;
    store8f(apB + quad*8, AaB0);
    store8f(apB + 32 + quad*8, AaB1);

    // ---- res0 = sum_k attn*(v+P), both points, shfl-reduce over 16 rows ----
    float w0[8], w1[8], y0[8], y1[8];
    #pragma unroll
    for (int j = 0; j < 8; j++){
      w0[j] = (float)AaA0[j] * ((float)VaA0[j] + (float)PaA0[j]);
      w1[j] = (float)AaA1[j] * ((float)VaA1[j] + (float)PaA1[j]);
      y0[j] = (float)AaB0[j] * ((float)VaB0[j] + (float)PaB0[j]);
      y1[j] = (float)AaB1[j] * ((float)VaB1[j] + (float)PaB1[j]);
    }
    #pragma unroll
    for (int mask = 1; mask < 16; mask <<= 1){
      #pragma unroll
      for (int j = 0; j < 8; j++){
        w0[j] += __shfl_xor(w0[j], mask);
        w1[j] += __shfl_xor(w1[j], mask);
        y0[j] += __shfl_xor(y0[j], mask);
        y1[j] += __shfl_xor(y1[j], mask);
      }
    }
    if (m16 == 0){
      half8 oA0, oA1, oB0, oB1;
      #pragma unroll
      for (int j = 0; j < 8; j++){
        oA0[j] = (_Float16)w0[j]; oA1[j] = (_Float16)w1[j];
        oB0[j] = (_Float16)y0[j]; oB1[j] = (_Float16)y1[j];
      }
      *(half8*)&r0[gptA*64 + quad*8] = oA0;
      *(half8*)&r0[gptA*64 + 32 + quad*8] = oA1;
      *(half8*)&r0[gptB*64 + quad*8] = oB0;
      *(half8*)&r0[gptB*64 + 32 + quad*8] = oB1;
    }

    // ---- next pair's xyz loads (knn results have had a full body to land) ----
    if (pp < PPW-2){
      growA = growA_n; growB = growB_n;
      xqA0 = xyz[(gptA+2)*3+0]; xqA1 = xyz[(gptA+2)*3+1]; xqA2 = xyz[(gptA+2)*3+2];
      xqB0 = xyz[(gptB+2)*3+0]; xqB1 = xyz[(gptB+2)*3+1]; xqB2 = xyz[(gptB+2)*3+2];
      xnA0 = xyz[growA_n*3+0]; xnA1 = xyz[growA_n*3+1]; xnA2 = xyz[growA_n*3+2];
      xnB0 = xyz[growB_n*3+0]; xnB1 = xyz[growB_n*3+1]; xnB2 = xyz[growB_n*3+2];
    }
  }
}

// ---------------- kernel 3: res = res0 @ fc2 + fc2_b + features ----------------
__global__ __launch_bounds__(256, 2) void k3_fc2(
    const _Float16* __restrict__ r0, const float* __restrict__ fc2w,
    const float* __restrict__ fc2b, const float* __restrict__ feat,
    float* __restrict__ out_res)
{
  __shared__ half8 S[512];
  const int tid = threadIdx.x;
  fill_w64(S, fc2w, tid);
  __syncthreads();

  const int wave = tid >> 6, lane = tid & 63, quad = lane >> 4, m16 = lane & 15;
  const int rowbase = blockIdx.x*64 + wave*16;
  float fb[4];
  #pragma unroll
  for (int nt = 0; nt < 4; nt++) fb[nt] = fc2b[nt*16 + m16];

  const half8 A0 = *(const half8*)&r0[(rowbase + m16)*64 + quad*8];
  const half8 A1 = *(const half8*)&r0[(rowbase + m16)*64 + 32 + quad*8];
  const floatx4 z4 = {0.f, 0.f, 0.f, 0.f};

  #pragma unroll
  for (int nt = 0; nt < 4; nt++){
    floatx4 acc = MFMA16(A0, S[nt*64 + lane], z4);
    acc = MFMA16(A1, S[(4 + nt)*64 + lane], acc);
    #pragma unroll
    for (int r = 0; r < 4; r++){
      const int rowg = rowbase + quad*4 + r;
      const int col  = nt*16 + m16;
      out_res[rowg*64 + col] = acc[r] + fb[nt] + feat[rowg*64 + col];
    }
  }
}

extern "C" void kernel_launch(void* const* d_in, const int* in_sizes, int n_in,
                              void* d_out, int out_size, void* d_ws, size_t ws_size,
                              hipStream_t stream)
{
  (void)in_sizes; (void)n_in; (void)out_size; (void)ws_size;
  const float* xyz  = (const float*)d_in[0];
  const float* feat = (const float*)d_in[1];
  const int*   knn  = (const int*)d_in[2];
  const float* fc1w = (const float*)d_in[3];
  const float* fc1b = (const float*)d_in[4];
  const float* fc2w = (const float*)d_in[5];
  const float* fc2b = (const float*)d_in[6];
  const float* d1w  = (const float*)d_in[7];
  const float* d1b  = (const float*)d_in[8];
  const float* d2w  = (const float*)d_in[9];
  const float* d2b  = (const float*)d_in[10];
  const float* g1w  = (const float*)d_in[11];
  const float* g1b  = (const float*)d_in[12];
  const float* g2w  = (const float*)d_in[13];
  const float* g2b  = (const float*)d_in[14];
  const float* wq   = (const float*)d_in[15];
  const float* wk   = (const float*)d_in[16];
  const float* wv   = (const float*)d_in[17];

  _Float16* ws  = (_Float16*)d_ws;
  _Float16* qws = ws;                      // TOT*64 halfs
  _Float16* kws = ws + (size_t)TOT*64;
  _Float16* vws = ws + (size_t)2*TOT*64;
  _Float16* r0  = ws + (size_t)3*TOT*64;

  float* out      = (float*)d_out;
  float* out_res  = out;                     // (B,N,64)
  float* out_attn = out + (size_t)TOT*64;    // (B,N,K,64)

  k1_qkv<<<TOT/64, 256, 0, stream>>>(feat, fc1w, fc1b, wq, wk, wv, qws, kws, vws);
  k2_point<<<TOT/(4*PPW), 256, 0, stream>>>(xyz, knn, d1w, d1b, d2w, d2b,
                                            g1w, g1b, g2w, g2b,
                                            qws, kws, vws, r0, out_attn);
  k3_fc2<<<TOT/64, 256, 0, stream>>>(r0, fc2w, fc2b, feat, out_res);
}

// Round 9
// 251.019 us; speedup vs baseline: 1.2342x; 1.0174x over previous
//
#include <hip/hip_runtime.h>
#include <hip/hip_bf16.h>

#define B_    4
#define N_    8192
#define TOT   (B_*N_)      // 32768 points
#define KNN_  16
#define PPW   8            // points per wave in k2
#define PITCH 80           // LDS tile pitch in halfs (160B, 16B-aligned rows)

typedef _Float16 half8  __attribute__((ext_vector_type(8)));
typedef float    floatx4 __attribute__((ext_vector_type(4)));

#define MFMA16(A, Bv, C) __builtin_amdgcn_mfma_f32_16x16x32_f16((A), (Bv), (C), 0, 0, 0)

__device__ __forceinline__ void lds_fence(){
  asm volatile("s_waitcnt lgkmcnt(0)" ::: "memory");
}
__device__ __forceinline__ half8 h8_load_f32(const float* __restrict__ p){
  float4 a = *(const float4*)p;
  float4 b = *(const float4*)(p + 4);
  half8 r;
  r[0] = (_Float16)a.x; r[1] = (_Float16)a.y; r[2] = (_Float16)a.z; r[3] = (_Float16)a.w;
  r[4] = (_Float16)b.x; r[5] = (_Float16)b.y; r[6] = (_Float16)b.z; r[7] = (_Float16)b.w;
  return r;
}
__device__ __forceinline__ void store8f(float* __restrict__ p, half8 v){
  float4 a = {(float)v[0], (float)v[1], (float)v[2], (float)v[3]};
  float4 b = {(float)v[4], (float)v[5], (float)v[6], (float)v[7]};
  *(float4*)p = a;
  *(float4*)(p + 4) = b;
}

// Fill LDS B-fragment array for a 64x64 row-major f32 weight.
// Layout: frag index (kt*4+nt)*64 + lane; lane holds W[kt*32+quad*8+j][nt*16+(lane&15)].
__device__ void fill_w64(half8* dst, const float* __restrict__ W, int tid){
  for (int i = tid; i < 512; i += 256){
    int lane = i & 63, nt = (i >> 6) & 3, kt = i >> 8;
    int n  = nt*16 + (lane & 15);
    int kb = kt*32 + ((lane >> 4) & 3)*8;
    half8 v;
    #pragma unroll
    for (int j = 0; j < 8; j++) v[j] = (_Float16)W[(kb + j)*64 + n];
    dst[i] = v;
  }
}

// ---------------- kernel 1: x = fc1(features); q/xk/xv = x @ {wq,wk,wv} ----------------
__global__ __launch_bounds__(256, 3) void k1_qkv(
    const float* __restrict__ feat, const float* __restrict__ fc1w, const float* __restrict__ fc1b,
    const float* __restrict__ wqw, const float* __restrict__ wkw, const float* __restrict__ wvw,
    _Float16* __restrict__ qws, _Float16* __restrict__ kws, _Float16* __restrict__ vws)
{
  __shared__ half8 Sfc1[512], Sq[512], Sk[512], Sv[512];
  __shared__ alignas(16) _Float16 xt[4][16*PITCH];
  const int tid = threadIdx.x;
  fill_w64(Sfc1, fc1w, tid);
  fill_w64(Sq, wqw, tid);
  fill_w64(Sk, wkw, tid);
  fill_w64(Sv, wvw, tid);
  __syncthreads();

  const int wave = tid >> 6, lane = tid & 63, quad = lane >> 4, m16 = lane & 15;
  _Float16* tx = &xt[wave][0];
  const int rowbase = blockIdx.x*64 + wave*16;
  float fb[4];
  #pragma unroll
  for (int nt = 0; nt < 4; nt++) fb[nt] = fc1b[nt*16 + m16];

  const int arow = rowbase + m16;
  half8 Fa0 = h8_load_f32(&feat[arow*64 + quad*8]);
  half8 Fa1 = h8_load_f32(&feat[arow*64 + 32 + quad*8]);
  const floatx4 z4 = {0.f, 0.f, 0.f, 0.f};

  #pragma unroll
  for (int nt = 0; nt < 4; nt++){
    floatx4 acc = MFMA16(Fa0, Sfc1[nt*64 + lane], z4);
    acc = MFMA16(Fa1, Sfc1[(4 + nt)*64 + lane], acc);
    const int col = nt*16 + m16;
    #pragma unroll
    for (int r = 0; r < 4; r++)
      tx[(quad*4 + r)*PITCH + col] = (_Float16)(acc[r] + fb[nt]);
  }
  lds_fence();
  const half8 Ax0 = *(const half8*)&tx[m16*PITCH + quad*8];
  const half8 Ax1 = *(const half8*)&tx[m16*PITCH + 32 + quad*8];

#define EMIT_QKV(S, OUT)                                                      \
  { _Pragma("unroll")                                                         \
    for (int nt = 0; nt < 4; nt++){                                           \
      floatx4 acc = MFMA16(Ax0, S[nt*64 + lane], z4);                         \
      acc = MFMA16(Ax1, S[(4 + nt)*64 + lane], acc);                          \
      _Pragma("unroll")                                                       \
      for (int r = 0; r < 4; r++)                                             \
        OUT[(rowbase + quad*4 + r)*64 + nt*16 + m16] = (_Float16)acc[r];      \
    } }
  EMIT_QKV(Sq, qws)
  EMIT_QKV(Sk, kws)
  EMIT_QKV(Sv, vws)
#undef EMIT_QKV
}

// ---------------- kernel 2: per-point fused pos_enc / attention ----------------
// vs round 8: (a) res0 computed in C-layout from A2/Pc/Vc regs -> the 128-bpermute
// 4-deep reduce chain becomes 4 products + 2 shuffles per nt; (b) attn store
// deferred one iteration via dedicated attn tiles -> 2 fences/pair, store latency
// hidden under next pair's MFMA stages.
__global__ __launch_bounds__(256, 2) void k2_point(
    const float* __restrict__ xyz, const int* __restrict__ knn,
    const float* __restrict__ d1w, const float* __restrict__ d1b,
    const float* __restrict__ d2w, const float* __restrict__ d2b,
    const float* __restrict__ g1w, const float* __restrict__ g1b,
    const float* __restrict__ g2w, const float* __restrict__ g2b,
    const _Float16* __restrict__ qws, const _Float16* __restrict__ kws,
    const _Float16* __restrict__ vws,
    _Float16* __restrict__ r0, float* __restrict__ attn_out)
{
  __shared__ half8 Sd2[512], Sg1[512], Sg2[512];
  __shared__ float4 Td1[64];                       // d1^T columns: {w0,w1,w2,bias}
  __shared__ alignas(16) _Float16 tiles[4][2][16*PITCH];   // P/u tiles (pair A/B)
  __shared__ alignas(16) _Float16 atile[4][2][16*PITCH];   // deferred attn tiles
  const int tid = threadIdx.x;
  fill_w64(Sd2, d2w, tid);
  fill_w64(Sg1, g1w, tid);
  fill_w64(Sg2, g2w, tid);
  if (tid < 64)
    Td1[tid] = make_float4(d1w[tid], d1w[64 + tid], d1w[128 + tid], d1b[tid]);
  __syncthreads();

  const int wave = tid >> 6, lane = tid & 63, quad = lane >> 4, m16 = lane & 15;
  _Float16* tT0 = &tiles[wave][0][0];
  _Float16* tT1 = &tiles[wave][1][0];
  _Float16* aT0 = &atile[wave][0][0];
  _Float16* aT1 = &atile[wave][1][0];

  half8 Fd2[2][4], Fg1[2][4], Fg2[2][4];
  #pragma unroll
  for (int nt = 0; nt < 4; nt++){
    #pragma unroll
    for (int kt = 0; kt < 2; kt++){
      Fd2[kt][nt] = Sd2[(kt*4 + nt)*64 + lane];
      Fg1[kt][nt] = Sg1[(kt*4 + nt)*64 + lane];
      Fg2[kt][nt] = Sg2[(kt*4 + nt)*64 + lane];
    }
  }
  float bd2[4], bg1[4], bg2[4];
  #pragma unroll
  for (int nt = 0; nt < 4; nt++){
    const int c = nt*16 + m16;
    bd2[nt] = d2b[c]; bg1[nt] = g1b[c]; bg2[nt] = g2b[c];
  }
  const floatx4 z4 = {0.f, 0.f, 0.f, 0.f};
  // XOR bank swizzle: write col' = col ^ (quad<<3); read col' = col ^ ((m16>>2)<<3).
  const int wsw = quad << 3;
  const int swz = (quad ^ (m16 >> 2)) << 3;

  // XCD-aware bijective block swizzle (grid 1024 = 8 XCDs x 128 chunks).
  const int swb  = (blockIdx.x & 7)*128 + (blockIdx.x >> 3);
  const int gpt0 = swb*(4*PPW) + wave*PPW;          // 32 consecutive points per block
  const int b    = gpt0 >> 13;                      // N=8192; constant within block

  // ---- pair-deep pipeline for the knn -> xyz gather chain ----
  int growA = b*N_ + knn[gpt0*KNN_ + m16];
  int growB = b*N_ + knn[(gpt0+1)*KNN_ + m16];
  float xqA0 = xyz[gpt0*3+0],     xqA1 = xyz[gpt0*3+1],     xqA2 = xyz[gpt0*3+2];
  float xqB0 = xyz[(gpt0+1)*3+0], xqB1 = xyz[(gpt0+1)*3+1], xqB2 = xyz[(gpt0+1)*3+2];
  float xnA0 = xyz[growA*3+0], xnA1 = xyz[growA*3+1], xnA2 = xyz[growA*3+2];
  float xnB0 = xyz[growB*3+0], xnB1 = xyz[growB*3+1], xnB2 = xyz[growB*3+2];

  int prevA = -1, prevB = -1;   // previous pair's points (deferred attn store)

  for (int pp = 0; pp < PPW; pp += 2){
    const int gptA = gpt0 + pp, gptB = gptA + 1;
    const int gA = growA, gB = growB;

    // ---- K/Q gathers, A-layout coalesced (16B/lane) ----
    const half8 KaA0 = *(const half8*)&kws[gA*64 + quad*8];
    const half8 KaA1 = *(const half8*)&kws[gA*64 + 32 + quad*8];
    const half8 QaA0 = *(const half8*)&qws[gptA*64 + quad*8];
    const half8 QaA1 = *(const half8*)&qws[gptA*64 + 32 + quad*8];
    const half8 KaB0 = *(const half8*)&kws[gB*64 + quad*8];
    const half8 KaB1 = *(const half8*)&kws[gB*64 + 32 + quad*8];
    const half8 QaB0 = *(const half8*)&qws[gptB*64 + quad*8];
    const half8 QaB1 = *(const half8*)&qws[gptB*64 + 32 + quad*8];

    // ---- V gathers in C-layout (this lane owns neighbor rows quad*4+r) ----
    const int gA0 = __shfl(gA, quad*4 + 0), gA1 = __shfl(gA, quad*4 + 1);
    const int gA2 = __shfl(gA, quad*4 + 2), gA3 = __shfl(gA, quad*4 + 3);
    const int gB0 = __shfl(gB, quad*4 + 0), gB1 = __shfl(gB, quad*4 + 1);
    const int gB2 = __shfl(gB, quad*4 + 2), gB3 = __shfl(gB, quad*4 + 3);
    _Float16 VcA[4][4], VcB[4][4];                 // [nt][r]
    #pragma unroll
    for (int nt = 0; nt < 4; nt++){
      const int c = nt*16 + m16;
      VcA[nt][0] = vws[gA0*64 + c]; VcA[nt][1] = vws[gA1*64 + c];
      VcA[nt][2] = vws[gA2*64 + c]; VcA[nt][3] = vws[gA3*64 + c];
      VcB[nt][0] = vws[gB0*64 + c]; VcB[nt][1] = vws[gB1*64 + c];
      VcB[nt][2] = vws[gB2*64 + c]; VcB[nt][3] = vws[gB3*64 + c];
    }

    // prefetch next pair's knn rows
    int growA_n = 0, growB_n = 0;
    if (pp < PPW-2){
      growA_n = b*N_ + knn[(gptA+2)*KNN_ + m16];
      growB_n = b*N_ + knn[(gptB+2)*KNN_ + m16];
    }

    const float dxA = xqA0 - xnA0, dyA = xqA1 - xnA1, dzA = xqA2 - xnA2;
    const float dxB = xqB0 - xnB0, dyB = xqB1 - xnB1, dzB = xqB2 - xnB2;

    // ---- stage 1 (both): t = relu(rel @ d1 + b), pure VALU ----
    half8 AtA0, AtA1, AtB0, AtB1;
    #pragma unroll
    for (int j = 0; j < 8; j++){
      const float4 w  = Td1[quad*8 + j];
      const float4 w2 = Td1[32 + quad*8 + j];
      float tA  = fmaf(dxA, w.x,  fmaf(dyA, w.y,  fmaf(dzA, w.z,  w.w)));
      float tA2 = fmaf(dxA, w2.x, fmaf(dyA, w2.y, fmaf(dzA, w2.z, w2.w)));
      float tB  = fmaf(dxB, w.x,  fmaf(dyB, w.y,  fmaf(dzB, w.z,  w.w)));
      float tB2 = fmaf(dxB, w2.x, fmaf(dyB, w2.y, fmaf(dzB, w2.z, w2.w)));
      AtA0[j] = (_Float16)(tA  > 0.f ? tA  : 0.f);
      AtA1[j] = (_Float16)(tA2 > 0.f ? tA2 : 0.f);
      AtB0[j] = (_Float16)(tB  > 0.f ? tB  : 0.f);
      AtB1[j] = (_Float16)(tB2 > 0.f ? tB2 : 0.f);
    }

    // ---- stage 2 (both): P = t @ d2 + b -> Pc regs + tiles ----
    float PcA[4][4], PcB[4][4];
    #pragma unroll
    for (int nt = 0; nt < 4; nt++){
      floatx4 accA = MFMA16(AtA0, Fd2[0][nt], z4);
      accA = MFMA16(AtA1, Fd2[1][nt], accA);
      floatx4 accB = MFMA16(AtB0, Fd2[0][nt], z4);
      accB = MFMA16(AtB1, Fd2[1][nt], accB);
      const int colS = (nt*16 + m16) ^ wsw;
      #pragma unroll
      for (int r = 0; r < 4; r++){
        PcA[nt][r] = accA[r] + bd2[nt];
        PcB[nt][r] = accB[r] + bd2[nt];
        tT0[(quad*4 + r)*PITCH + colS] = (_Float16)PcA[nt][r];
        tT1[(quad*4 + r)*PITCH + colS] = (_Float16)PcB[nt][r];
      }
    }
    lds_fence();                                            // fence 1

    // ---- deferred attn store of the PREVIOUS pair (reads covered by fence 1;
    //      global-store latency hides under stages 3-4) ----
    if (prevA >= 0){
      const half8 pA0 = *(const half8*)&aT0[m16*PITCH + swz];
      const half8 pA1 = *(const half8*)&aT0[m16*PITCH + 32 + swz];
      const half8 pB0 = *(const half8*)&aT1[m16*PITCH + swz];
      const half8 pB1 = *(const half8*)&aT1[m16*PITCH + 32 + swz];
      float* apA = attn_out + ((size_t)prevA*KNN_ + m16)*64;
      store8f(apA + quad*8, pA0);
      store8f(apA + 32 + quad*8, pA1);
      float* apB = attn_out + ((size_t)prevB*KNN_ + m16)*64;
      store8f(apB + quad*8, pB0);
      store8f(apB + 32 + quad*8, pB1);
    }

    const half8 PaA0 = *(const half8*)&tT0[m16*PITCH + swz];
    const half8 PaA1 = *(const half8*)&tT0[m16*PITCH + 32 + swz];
    const half8 PaB0 = *(const half8*)&tT1[m16*PITCH + swz];
    const half8 PaB1 = *(const half8*)&tT1[m16*PITCH + 32 + swz];
    const half8 HA0 = QaA0 - KaA0 + PaA0;
    const half8 HA1 = QaA1 - KaA1 + PaA1;
    const half8 HB0 = QaB0 - KaB0 + PaB0;
    const half8 HB1 = QaB1 - KaB1 + PaB1;

    // ---- stage 3 (both): u = relu(H @ g1 + b) -> tiles ----
    #pragma unroll
    for (int nt = 0; nt < 4; nt++){
      floatx4 accA = MFMA16(HA0, Fg1[0][nt], z4);
      accA = MFMA16(HA1, Fg1[1][nt], accA);
      floatx4 accB = MFMA16(HB0, Fg1[0][nt], z4);
      accB = MFMA16(HB1, Fg1[1][nt], accB);
      const int colS = (nt*16 + m16) ^ wsw;
      #pragma unroll
      for (int r = 0; r < 4; r++){
        float tA = accA[r] + bg1[nt];
        float tB = accB[r] + bg1[nt];
        tT0[(quad*4 + r)*PITCH + colS] = (_Float16)(tA > 0.f ? tA : 0.f);
        tT1[(quad*4 + r)*PITCH + colS] = (_Float16)(tB > 0.f ? tB : 0.f);
      }
    }
    lds_fence();                                            // fence 2
    const half8 UA0 = *(const half8*)&tT0[m16*PITCH + swz];
    const half8 UA1 = *(const half8*)&tT0[m16*PITCH + 32 + swz];
    const half8 UB0 = *(const half8*)&tT1[m16*PITCH + swz];
    const half8 UB1 = *(const half8*)&tT1[m16*PITCH + 32 + swz];

    // ---- stage 4 (both): logits = u @ g2 + b -> softmax in C-layout regs ----
    float A2A[4][4], A2B[4][4];
    #pragma unroll
    for (int nt = 0; nt < 4; nt++){
      floatx4 accA = MFMA16(UA0, Fg2[0][nt], z4);
      accA = MFMA16(UA1, Fg2[1][nt], accA);
      floatx4 accB = MFMA16(UB0, Fg2[0][nt], z4);
      accB = MFMA16(UB1, Fg2[1][nt], accB);
      #pragma unroll
      for (int r = 0; r < 4; r++){ A2A[nt][r] = accA[r] + bg2[nt]; A2B[nt][r] = accB[r] + bg2[nt]; }
    }
    #pragma unroll
    for (int nt = 0; nt < 4; nt++){
      float mxA = fmaxf(fmaxf(A2A[nt][0], A2A[nt][1]), fmaxf(A2A[nt][2], A2A[nt][3]));
      float mxB = fmaxf(fmaxf(A2B[nt][0], A2B[nt][1]), fmaxf(A2B[nt][2], A2B[nt][3]));
      mxA = fmaxf(mxA, __shfl_xor(mxA, 16));
      mxB = fmaxf(mxB, __shfl_xor(mxB, 16));
      mxA = fmaxf(mxA, __shfl_xor(mxA, 32));
      mxB = fmaxf(mxB, __shfl_xor(mxB, 32));
      float sA = 0.f, sB = 0.f;
      #pragma unroll
      for (int r = 0; r < 4; r++){
        float eA = exp2f((A2A[nt][r] - mxA)*0.18033688011112042f);  // /8, base-2
        float eB = exp2f((A2B[nt][r] - mxB)*0.18033688011112042f);
        A2A[nt][r] = eA; sA += eA;
        A2B[nt][r] = eB; sB += eB;
      }
      sA += __shfl_xor(sA, 16);
      sB += __shfl_xor(sB, 16);
      sA += __shfl_xor(sA, 32);
      sB += __shfl_xor(sB, 32);
      const float invA = __builtin_amdgcn_rcpf(sA);
      const float invB = __builtin_amdgcn_rcpf(sB);
      #pragma unroll
      for (int r = 0; r < 4; r++){ A2A[nt][r] *= invA; A2B[nt][r] *= invB; }
      // stash normalized attn into the deferred-store tiles (no fence here)
      const int colS = (nt*16 + m16) ^ wsw;
      #pragma unroll
      for (int r = 0; r < 4; r++){
        aT0[(quad*4 + r)*PITCH + colS] = (_Float16)A2A[nt][r];
        aT1[(quad*4 + r)*PITCH + colS] = (_Float16)A2B[nt][r];
      }
    }

    // ---- res0 in C-layout: sum over nb = quad*4+r then cross-quad (2 shuffles) ----
    #pragma unroll
    for (int nt = 0; nt < 4; nt++){
      float sA = A2A[nt][0]*((float)VcA[nt][0] + PcA[nt][0])
               + A2A[nt][1]*((float)VcA[nt][1] + PcA[nt][1])
               + A2A[nt][2]*((float)VcA[nt][2] + PcA[nt][2])
               + A2A[nt][3]*((float)VcA[nt][3] + PcA[nt][3]);
      float sB = A2B[nt][0]*((float)VcB[nt][0] + PcB[nt][0])
               + A2B[nt][1]*((float)VcB[nt][1] + PcB[nt][1])
               + A2B[nt][2]*((float)VcB[nt][2] + PcB[nt][2])
               + A2B[nt][3]*((float)VcB[nt][3] + PcB[nt][3]);
      sA += __shfl_xor(sA, 16);
      sB += __shfl_xor(sB, 16);
      sA += __shfl_xor(sA, 32);
      sB += __shfl_xor(sB, 32);
      if (quad == 0){
        r0[gptA*64 + nt*16 + m16] = (_Float16)sA;
        r0[gptB*64 + nt*16 + m16] = (_Float16)sB;
      }
    }

    prevA = gptA; prevB = gptB;

    // ---- next pair's xyz loads (knn results have had a full body to land) ----
    if (pp < PPW-2){
      growA = growA_n; growB = growB_n;
      xqA0 = xyz[(gptA+2)*3+0]; xqA1 = xyz[(gptA+2)*3+1]; xqA2 = xyz[(gptA+2)*3+2];
      xqB0 = xyz[(gptB+2)*3+0]; xqB1 = xyz[(gptB+2)*3+1]; xqB2 = xyz[(gptB+2)*3+2];
      xnA0 = xyz[growA_n*3+0]; xnA1 = xyz[growA_n*3+1]; xnA2 = xyz[growA_n*3+2];
      xnB0 = xyz[growB_n*3+0]; xnB1 = xyz[growB_n*3+1]; xnB2 = xyz[growB_n*3+2];
    }
  }

  // ---- drain: store the final pair's attn ----
  lds_fence();
  {
    const half8 pA0 = *(const half8*)&aT0[m16*PITCH + swz];
    const half8 pA1 = *(const half8*)&aT0[m16*PITCH + 32 + swz];
    const half8 pB0 = *(const half8*)&aT1[m16*PITCH + swz];
    const half8 pB1 = *(const half8*)&aT1[m16*PITCH + 32 + swz];
    float* apA = attn_out + ((size_t)prevA*KNN_ + m16)*64;
    store8f(apA + quad*8, pA0);
    store8f(apA + 32 + quad*8, pA1);
    float* apB = attn_out + ((size_t)prevB*KNN_ + m16)*64;
    store8f(apB + quad*8, pB0);
    store8f(apB + 32 + quad*8, pB1);
  }
}

// ---------------- kernel 3: res = res0 @ fc2 + fc2_b + features ----------------
__global__ __launch_bounds__(256, 2) void k3_fc2(
    const _Float16* __restrict__ r0, const float* __restrict__ fc2w,
    const float* __restrict__ fc2b, const float* __restrict__ feat,
    float* __restrict__ out_res)
{
  __shared__ half8 S[512];
  const int tid = threadIdx.x;
  fill_w64(S, fc2w, tid);
  __syncthreads();

  const int wave = tid >> 6, lane = tid & 63, quad = lane >> 4, m16 = lane & 15;
  const int rowbase = blockIdx.x*64 + wave*16;
  float fb[4];
  #pragma unroll
  for (int nt = 0; nt < 4; nt++) fb[nt] = fc2b[nt*16 + m16];

  const half8 A0 = *(const half8*)&r0[(rowbase + m16)*64 + quad*8];
  const half8 A1 = *(const half8*)&r0[(rowbase + m16)*64 + 32 + quad*8];
  const floatx4 z4 = {0.f, 0.f, 0.f, 0.f};

  #pragma unroll
  for (int nt = 0; nt < 4; nt++){
    floatx4 acc = MFMA16(A0, S[nt*64 + lane], z4);
    acc = MFMA16(A1, S[(4 + nt)*64 + lane], acc);
    #pragma unroll
    for (int r = 0; r < 4; r++){
      const int rowg = rowbase + quad*4 + r;
      const int col  = nt*16 + m16;
      out_res[rowg*64 + col] = acc[r] + fb[nt] + feat[rowg*64 + col];
    }
  }
}

extern "C" void kernel_launch(void* const* d_in, const int* in_sizes, int n_in,
                              void* d_out, int out_size, void* d_ws, size_t ws_size,
                              hipStream_t stream)
{
  (void)in_sizes; (void)n_in; (void)out_size; (void)ws_size;
  const float* xyz  = (const float*)d_in[0];
  const float* feat = (const float*)d_in[1];
  const int*   knn  = (const int*)d_in[2];
  const float* fc1w = (const float*)d_in[3];
  const float* fc1b = (const float*)d_in[4];
  const float* fc2w = (const float*)d_in[5];
  const float* fc2b = (const float*)d_in[6];
  const float* d1w  = (const float*)d_in[7];
  const float* d1b  = (const float*)d_in[8];
  const float* d2w  = (const float*)d_in[9];
  const float* d2b  = (const float*)d_in[10];
  const float* g1w  = (const float*)d_in[11];
  const float* g1b  = (const float*)d_in[12];
  const float* g2w  = (const float*)d_in[13];
  const float* g2b  = (const float*)d_in[14];
  const float* wq   = (const float*)d_in[15];
  const float* wk   = (const float*)d_in[16];
  const float* wv   = (const float*)d_in[17];

  _Float16* ws  = (_Float16*)d_ws;
  _Float16* qws = ws;                      // TOT*64 halfs
  _Float16* kws = ws + (size_t)TOT*64;
  _Float16* vws = ws + (size_t)2*TOT*64;
  _Float16* r0  = ws + (size_t)3*TOT*64;

  float* out      = (float*)d_out;
  float* out_res  = out;                     // (B,N,64)
  float* out_attn = out + (size_t)TOT*64;    // (B,N,K,64)

  k1_qkv<<<TOT/64, 256, 0, stream>>>(feat, fc1w, fc1b, wq, wk, wv, qws, kws, vws);
  k2_point<<<TOT/(4*PPW), 256, 0, stream>>>(xyz, knn, d1w, d1b, d2w, d2b,
                                            g1w, g1b, g2w, g2b,
                                            qws, kws, vws, r0, out_attn);
  k3_fc2<<<TOT/64, 256, 0, stream>>>(r0, fc2w, fc2b, feat, out_res);
}